// Round 1
// baseline (1012.899 us; speedup 1.0000x reference)
//
#include <hip/hip_runtime.h>

static constexpr int NNODE = 100000;
static constexpr int NEDGE = 1600000;
static constexpr int EPOS  = 100000;
static constexpr int ENEG  = 500000;
static constexpr int F     = 128;
static constexpr int CLS   = 16;
static constexpr int NPAD  = 100352;   // 98 * 1024, >= NNODE
static constexpr int NB    = 98;       // scan blocks (1024 elems each)

// ---------------- CSR build ----------------

__global__ void k_degree(const int* __restrict__ dst, int* __restrict__ deg) {
    int e = blockIdx.x * 256 + threadIdx.x;
    if (e < NEDGE) atomicAdd(&deg[dst[e]], 1);
}

__global__ void k_scan1(const int* __restrict__ deg, int* __restrict__ rp,
                        int* __restrict__ bsum) {
    __shared__ int s[256];
    const int t = threadIdx.x;
    const int base = blockIdx.x * 1024 + t * 4;
    const int v0 = deg[base], v1 = deg[base + 1], v2 = deg[base + 2], v3 = deg[base + 3];
    const int tsum = v0 + v1 + v2 + v3;
    s[t] = tsum;
    __syncthreads();
    for (int off = 1; off < 256; off <<= 1) {
        int val = (t >= off) ? s[t - off] : 0;
        __syncthreads();
        s[t] += val;
        __syncthreads();
    }
    const int excl = s[t] - tsum;
    rp[base]     = excl;
    rp[base + 1] = excl + v0;
    rp[base + 2] = excl + v0 + v1;
    rp[base + 3] = excl + v0 + v1 + v2;
    if (t == 255) bsum[blockIdx.x] = s[255];
}

__global__ void k_scan2(const int* __restrict__ bsum, int* __restrict__ boff) {
    if (threadIdx.x == 0 && blockIdx.x == 0) {
        int run = 0;
        for (int b = 0; b < NB; ++b) { boff[b] = run; run += bsum[b]; }
    }
}

__global__ void k_scan3(int* __restrict__ rp, const int* __restrict__ boff) {
    int i = blockIdx.x * 256 + threadIdx.x;   // i < NPAD
    rp[i] += boff[i >> 10];
}

__global__ void k_scatter(const int* __restrict__ src, const int* __restrict__ dst,
                          const int* __restrict__ rp, int* __restrict__ cnt,
                          int* __restrict__ col) {
    int e = blockIdx.x * 256 + threadIdx.x;
    if (e < NEDGE) {
        const int d = dst[e];
        const int p = rp[d] + atomicAdd(&cnt[d], 1);
        col[p] = src[e];
    }
}

// ---------------- fused aggregate + linear layers ----------------

__device__ __forceinline__ void load_and_aggregate(
    const float* __restrict__ hin, const int* __restrict__ rowptr,
    const int* __restrict__ deg, const int* __restrict__ col,
    int bbase, float (*hT)[F], float (*aT)[F]) {
    const int tid  = threadIdx.x;
    const int lane = tid & 31;
    const int gid  = tid >> 5;
    for (int r = 0; r < 2; ++r) {
        const int ln = gid + r * 8;
        const int n  = bbase + ln;
        const float4 self = *(const float4*)(hin + (size_t)n * F + lane * 4);
        float sx = 0.f, sy = 0.f, sz = 0.f, sw = 0.f;
        const int p0 = rowptr[n];
        const int d  = deg[n];
        for (int p = p0; p < p0 + d; ++p) {
            const int u = col[p];
            const float4 t = *(const float4*)(hin + (size_t)u * F + lane * 4);
            sx += t.x; sy += t.y; sz += t.z; sw += t.w;
        }
        const float inv = d > 0 ? 1.0f / (float)d : 0.0f;
        *(float4*)&hT[ln][lane * 4] = self;
        float4 av; av.x = sx * inv; av.y = sy * inv; av.z = sz * inv; av.w = sw * inv;
        *(float4*)&aT[ln][lane * 4] = av;
    }
}

// 16 nodes per block, 256 threads. out = relu(h@Ws + agg@Wn + b), FOUT=128.
__global__ __launch_bounds__(256) void k_layer128(
    const float* __restrict__ hin, const int* __restrict__ rowptr,
    const int* __restrict__ deg, const int* __restrict__ col,
    const float* __restrict__ Ws, const float* __restrict__ Wn,
    const float* __restrict__ bias, float* __restrict__ hout) {
    __shared__ float hT[16][F];
    __shared__ float aT[16][F];
    __shared__ float WsT[16][F];
    __shared__ float WnT[16][F];
    const int tid = threadIdx.x;
    const int bbase = blockIdx.x * 16;

    load_and_aggregate(hin, rowptr, deg, col, bbase, hT, aT);

    const int c4 = tid & 31;      // col quad: cols c4*4 .. c4*4+3
    const int g  = tid >> 5;      // 8 groups, 2 nodes each
    const int n0 = g * 2, n1 = g * 2 + 1;
    float4 acc0 = {0, 0, 0, 0}, acc1 = {0, 0, 0, 0};

    for (int kc = 0; kc < 8; ++kc) {
        __syncthreads();          // protect W tile reuse (and hT first time)
        {
            const float4* wsg = (const float4*)(Ws + kc * 2048);
            const float4* wng = (const float4*)(Wn + kc * 2048);
            float4* wsl = (float4*)&WsT[0][0];
            float4* wnl = (float4*)&WnT[0][0];
            wsl[tid]       = wsg[tid];
            wsl[tid + 256] = wsg[tid + 256];
            wnl[tid]       = wng[tid];
            wnl[tid + 256] = wng[tid + 256];
        }
        __syncthreads();
        #pragma unroll
        for (int kq = 0; kq < 4; ++kq) {
            const int kb = kc * 16 + kq * 4;
            const float4 h0 = *(const float4*)&hT[n0][kb];
            const float4 a0 = *(const float4*)&aT[n0][kb];
            const float4 h1 = *(const float4*)&hT[n1][kb];
            const float4 a1 = *(const float4*)&aT[n1][kb];
            const float hs0[4] = {h0.x, h0.y, h0.z, h0.w};
            const float as0[4] = {a0.x, a0.y, a0.z, a0.w};
            const float hs1[4] = {h1.x, h1.y, h1.z, h1.w};
            const float as1[4] = {a1.x, a1.y, a1.z, a1.w};
            #pragma unroll
            for (int j = 0; j < 4; ++j) {
                const float4 ws = *(const float4*)&WsT[kq * 4 + j][c4 * 4];
                const float4 wn = *(const float4*)&WnT[kq * 4 + j][c4 * 4];
                acc0.x += ws.x * hs0[j] + wn.x * as0[j];
                acc0.y += ws.y * hs0[j] + wn.y * as0[j];
                acc0.z += ws.z * hs0[j] + wn.z * as0[j];
                acc0.w += ws.w * hs0[j] + wn.w * as0[j];
                acc1.x += ws.x * hs1[j] + wn.x * as1[j];
                acc1.y += ws.y * hs1[j] + wn.y * as1[j];
                acc1.z += ws.z * hs1[j] + wn.z * as1[j];
                acc1.w += ws.w * hs1[j] + wn.w * as1[j];
            }
        }
    }

    const float4 bv = *(const float4*)(bias + c4 * 4);
    acc0.x = fmaxf(acc0.x + bv.x, 0.f); acc0.y = fmaxf(acc0.y + bv.y, 0.f);
    acc0.z = fmaxf(acc0.z + bv.z, 0.f); acc0.w = fmaxf(acc0.w + bv.w, 0.f);
    acc1.x = fmaxf(acc1.x + bv.x, 0.f); acc1.y = fmaxf(acc1.y + bv.y, 0.f);
    acc1.z = fmaxf(acc1.z + bv.z, 0.f); acc1.w = fmaxf(acc1.w + bv.w, 0.f);
    *(float4*)(hout + (size_t)(bbase + n0) * F + c4 * 4) = acc0;
    *(float4*)(hout + (size_t)(bbase + n1) * F + c4 * 4) = acc1;
}

// Final layer: FOUT=16, no relu.
__global__ __launch_bounds__(256) void k_layer16(
    const float* __restrict__ hin, const int* __restrict__ rowptr,
    const int* __restrict__ deg, const int* __restrict__ col,
    const float* __restrict__ Ws, const float* __restrict__ Wn,
    const float* __restrict__ bias, float* __restrict__ hout) {
    __shared__ float hT[16][F];
    __shared__ float aT[16][F];
    __shared__ float WsT[CLS][132];   // transposed [c][k], padded
    __shared__ float WnT[CLS][132];
    const int tid = threadIdx.x;
    const int bbase = blockIdx.x * 16;

    load_and_aggregate(hin, rowptr, deg, col, bbase, hT, aT);

    for (int i = tid; i < F * CLS; i += 256) {
        const int k = i >> 4, c = i & 15;
        WsT[c][k] = Ws[i];
        WnT[c][k] = Wn[i];
    }
    __syncthreads();

    const int c  = tid & 15;
    const int nl = tid >> 4;
    float acc = 0.f;
    #pragma unroll
    for (int kq = 0; kq < 32; ++kq) {
        const float4 h  = *(const float4*)&hT[nl][kq * 4];
        const float4 a  = *(const float4*)&aT[nl][kq * 4];
        const float4 ws = *(const float4*)&WsT[c][kq * 4];
        const float4 wn = *(const float4*)&WnT[c][kq * 4];
        acc += h.x * ws.x + h.y * ws.y + h.z * ws.z + h.w * ws.w;
        acc += a.x * wn.x + a.y * wn.y + a.z * wn.z + a.w * wn.w;
    }
    acc += bias[c];
    hout[(size_t)(bbase + nl) * CLS + c] = acc;
}

// ---------------- edge scoring ----------------

__global__ void k_score(const float* __restrict__ H3,
                        const int* __restrict__ pu, const int* __restrict__ pv,
                        const int* __restrict__ nu, const int* __restrict__ nv,
                        float* __restrict__ out) {
    int i = blockIdx.x * 256 + threadIdx.x;
    if (i >= EPOS + ENEG) return;
    int u, v, o;
    if (i < EPOS) { u = pu[i]; v = pv[i]; o = i; }
    else { int j = i - EPOS; u = nu[j]; v = nv[j]; o = EPOS + j; }
    const float4* a = (const float4*)(H3 + (size_t)u * CLS);
    const float4* b = (const float4*)(H3 + (size_t)v * CLS);
    float s = 0.f;
    #pragma unroll
    for (int r = 0; r < 4; ++r) {
        const float4 av = a[r], bv = b[r];
        s += av.x * bv.x + av.y * bv.y + av.z * bv.z + av.w * bv.w;
    }
    out[o] = s;
}

// ---------------- launch ----------------

extern "C" void kernel_launch(void* const* d_in, const int* in_sizes, int n_in,
                              void* d_out, int out_size, void* d_ws, size_t ws_size,
                              hipStream_t stream) {
    const float* x     = (const float*)d_in[0];
    const int*   src   = (const int*)d_in[1];
    const int*   dst   = (const int*)d_in[2];
    const int*   pos_u = (const int*)d_in[3];
    const int*   pos_v = (const int*)d_in[4];
    const int*   neg_u = (const int*)d_in[5];
    const int*   neg_v = (const int*)d_in[6];
    const float* W1s = (const float*)d_in[7];
    const float* W1n = (const float*)d_in[8];
    const float* b1  = (const float*)d_in[9];
    const float* W2s = (const float*)d_in[10];
    const float* W2n = (const float*)d_in[11];
    const float* b2  = (const float*)d_in[12];
    const float* W3s = (const float*)d_in[13];
    const float* W3n = (const float*)d_in[14];
    const float* b3  = (const float*)d_in[15];
    float* out = (float*)d_out;

    char* ws = (char*)d_ws;
    int*   deg  = (int*)(ws);                                  // NPAD
    int*   rp   = (int*)(ws + (size_t)NPAD * 4);               // NPAD
    int*   cnt  = (int*)(ws + (size_t)NPAD * 8);               // NPAD
    int*   bsum = (int*)(ws + (size_t)NPAD * 12);              // 128
    int*   boff = (int*)(ws + (size_t)NPAD * 12 + 512);        // 128
    int*   col  = (int*)(ws + (size_t)NPAD * 12 + 1024);       // NEDGE
    size_t hoff = (size_t)NPAD * 12 + 1024 + (size_t)NEDGE * 4;
    hoff = (hoff + 255) & ~(size_t)255;
    float* H1 = (float*)(ws + hoff);                           // N*F
    float* H2 = (float*)(ws + hoff + (size_t)NNODE * F * 4);   // N*F
    float* H3 = H1;                                            // N*CLS (reuse)

    hipMemsetAsync(deg, 0, (size_t)NPAD * 4, stream);
    hipMemsetAsync(cnt, 0, (size_t)NPAD * 4, stream);

    k_degree<<<NEDGE / 256, 256, 0, stream>>>(dst, deg);
    k_scan1<<<NB, 256, 0, stream>>>(deg, rp, bsum);
    k_scan2<<<1, 64, 0, stream>>>(bsum, boff);
    k_scan3<<<NPAD / 256, 256, 0, stream>>>(rp, boff);
    k_scatter<<<NEDGE / 256, 256, 0, stream>>>(src, dst, rp, cnt, col);

    k_layer128<<<NNODE / 16, 256, 0, stream>>>(x,  rp, deg, col, W1s, W1n, b1, H1);
    k_layer128<<<NNODE / 16, 256, 0, stream>>>(H1, rp, deg, col, W2s, W2n, b2, H2);
    k_layer16 <<<NNODE / 16, 256, 0, stream>>>(H2, rp, deg, col, W3s, W3n, b3, H3);

    k_score<<<(EPOS + ENEG + 255) / 256, 256, 0, stream>>>(H3, pos_u, pos_v,
                                                           neg_u, neg_v, out);
}

// Round 2
// 788.990 us; speedup vs baseline: 1.2838x; 1.2838x over previous
//
#include <hip/hip_runtime.h>

static constexpr int NNODE = 100000;
static constexpr int NEDGE = 1600000;
static constexpr int EPOS  = 100000;
static constexpr int ENEG  = 500000;
static constexpr int F     = 128;
static constexpr int CLS   = 16;
static constexpr int NPAD  = 100352;   // 98 * 1024, >= NNODE
static constexpr int NB    = 98;       // scan blocks (1024 elems each)

// ---------------- bf16 helpers ----------------

__device__ __forceinline__ ushort f2b(float f) {           // f32 -> bf16 RNE
    unsigned u = __float_as_uint(f);
    unsigned r = u + 0x7fffu + ((u >> 16) & 1u);
    return (ushort)(r >> 16);
}
__device__ __forceinline__ float b2f(ushort h) {
    return __uint_as_float(((unsigned)h) << 16);
}
__device__ __forceinline__ float4 b2f4(ushort4 v) {
    float4 r;
    r.x = b2f(v.x); r.y = b2f(v.y); r.z = b2f(v.z); r.w = b2f(v.w);
    return r;
}

__global__ void k_cast(const float* __restrict__ x, ushort* __restrict__ xb) {
    int i = blockIdx.x * 256 + threadIdx.x;   // one float4 per thread
    float4 v = ((const float4*)x)[i];
    ushort4 o; o.x = f2b(v.x); o.y = f2b(v.y); o.z = f2b(v.z); o.w = f2b(v.w);
    ((ushort4*)xb)[i] = o;
}

// ---------------- CSR build ----------------

__global__ void k_degree(const int* __restrict__ dst, int* __restrict__ deg) {
    int e = blockIdx.x * 256 + threadIdx.x;
    if (e < NEDGE) atomicAdd(&deg[dst[e]], 1);
}

__global__ void k_scan1(const int* __restrict__ deg, int* __restrict__ rp,
                        int* __restrict__ bsum) {
    __shared__ int s[256];
    const int t = threadIdx.x;
    const int base = blockIdx.x * 1024 + t * 4;
    const int v0 = deg[base], v1 = deg[base + 1], v2 = deg[base + 2], v3 = deg[base + 3];
    const int tsum = v0 + v1 + v2 + v3;
    s[t] = tsum;
    __syncthreads();
    for (int off = 1; off < 256; off <<= 1) {
        int val = (t >= off) ? s[t - off] : 0;
        __syncthreads();
        s[t] += val;
        __syncthreads();
    }
    const int excl = s[t] - tsum;
    rp[base]     = excl;
    rp[base + 1] = excl + v0;
    rp[base + 2] = excl + v0 + v1;
    rp[base + 3] = excl + v0 + v1 + v2;
    if (t == 255) bsum[blockIdx.x] = s[255];
}

__global__ void k_scan2(const int* __restrict__ bsum, int* __restrict__ boff) {
    if (threadIdx.x == 0 && blockIdx.x == 0) {
        int run = 0;
        for (int b = 0; b < NB; ++b) { boff[b] = run; run += bsum[b]; }
    }
}

__global__ void k_scan3(int* __restrict__ rp, const int* __restrict__ boff) {
    int i = blockIdx.x * 256 + threadIdx.x;   // i < NPAD
    rp[i] += boff[i >> 10];
}

__global__ void k_scatter(const int* __restrict__ src, const int* __restrict__ dst,
                          const int* __restrict__ rp, int* __restrict__ cnt,
                          int* __restrict__ col) {
    int e = blockIdx.x * 256 + threadIdx.x;
    if (e < NEDGE) {
        const int d = dst[e];
        const int p = rp[d] + atomicAdd(&cnt[d], 1);
        col[p] = src[e];
    }
}

// ---------------- fused aggregate + linear layers (bf16 inputs) ----------------

__device__ __forceinline__ void load_and_aggregate_b(
    const ushort* __restrict__ hin, const int* __restrict__ rowptr,
    const int* __restrict__ deg, const int* __restrict__ col,
    int bbase, float (*hT)[F], float (*aT)[F]) {
    const int tid  = threadIdx.x;
    const int lane = tid & 31;
    const int gid  = tid >> 5;
    for (int r = 0; r < 2; ++r) {
        const int ln = gid + r * 8;
        const int n  = bbase + ln;
        const float4 self = b2f4(*(const ushort4*)(hin + (size_t)n * F + lane * 4));
        const int p0 = rowptr[n];
        const int d  = deg[n];
        const int pe = p0 + d;
        float4 s0 = {0, 0, 0, 0}, s1 = {0, 0, 0, 0};
        int p = p0;
        for (; p + 2 <= pe; p += 2) {
            const int u0 = col[p];
            const int u1 = col[p + 1];
            const ushort4 t0 = *(const ushort4*)(hin + (size_t)u0 * F + lane * 4);
            const ushort4 t1 = *(const ushort4*)(hin + (size_t)u1 * F + lane * 4);
            const float4 f0 = b2f4(t0);
            const float4 f1 = b2f4(t1);
            s0.x += f0.x; s0.y += f0.y; s0.z += f0.z; s0.w += f0.w;
            s1.x += f1.x; s1.y += f1.y; s1.z += f1.z; s1.w += f1.w;
        }
        if (p < pe) {
            const float4 f0 = b2f4(*(const ushort4*)(hin + (size_t)col[p] * F + lane * 4));
            s0.x += f0.x; s0.y += f0.y; s0.z += f0.z; s0.w += f0.w;
        }
        const float inv = d > 0 ? 1.0f / (float)d : 0.0f;
        *(float4*)&hT[ln][lane * 4] = self;
        float4 av;
        av.x = (s0.x + s1.x) * inv; av.y = (s0.y + s1.y) * inv;
        av.z = (s0.z + s1.z) * inv; av.w = (s0.w + s1.w) * inv;
        *(float4*)&aT[ln][lane * 4] = av;
    }
}

// 16 nodes per block, 256 threads. out = relu(h@Ws + agg@Wn + b) -> bf16, FOUT=128.
__global__ __launch_bounds__(256) void k_layer128(
    const ushort* __restrict__ hin, const int* __restrict__ rowptr,
    const int* __restrict__ deg, const int* __restrict__ col,
    const float* __restrict__ Ws, const float* __restrict__ Wn,
    const float* __restrict__ bias, ushort* __restrict__ hout) {
    __shared__ float hT[16][F];
    __shared__ float aT[16][F];
    __shared__ float WsT[16][F];
    __shared__ float WnT[16][F];
    const int tid = threadIdx.x;
    const int bbase = blockIdx.x * 16;

    load_and_aggregate_b(hin, rowptr, deg, col, bbase, hT, aT);

    const int c4 = tid & 31;      // col quad: cols c4*4 .. c4*4+3
    const int g  = tid >> 5;      // 8 groups, 2 nodes each
    const int n0 = g * 2, n1 = g * 2 + 1;
    float4 acc0 = {0, 0, 0, 0}, acc1 = {0, 0, 0, 0};

    for (int kc = 0; kc < 8; ++kc) {
        __syncthreads();          // protect W tile reuse (and hT first time)
        {
            const float4* wsg = (const float4*)(Ws + kc * 2048);
            const float4* wng = (const float4*)(Wn + kc * 2048);
            float4* wsl = (float4*)&WsT[0][0];
            float4* wnl = (float4*)&WnT[0][0];
            wsl[tid]       = wsg[tid];
            wsl[tid + 256] = wsg[tid + 256];
            wnl[tid]       = wng[tid];
            wnl[tid + 256] = wng[tid + 256];
        }
        __syncthreads();
        #pragma unroll
        for (int kq = 0; kq < 4; ++kq) {
            const int kb = kc * 16 + kq * 4;
            const float4 h0 = *(const float4*)&hT[n0][kb];
            const float4 a0 = *(const float4*)&aT[n0][kb];
            const float4 h1 = *(const float4*)&hT[n1][kb];
            const float4 a1 = *(const float4*)&aT[n1][kb];
            const float hs0[4] = {h0.x, h0.y, h0.z, h0.w};
            const float as0[4] = {a0.x, a0.y, a0.z, a0.w};
            const float hs1[4] = {h1.x, h1.y, h1.z, h1.w};
            const float as1[4] = {a1.x, a1.y, a1.z, a1.w};
            #pragma unroll
            for (int j = 0; j < 4; ++j) {
                const float4 ws = *(const float4*)&WsT[kq * 4 + j][c4 * 4];
                const float4 wn = *(const float4*)&WnT[kq * 4 + j][c4 * 4];
                acc0.x += ws.x * hs0[j] + wn.x * as0[j];
                acc0.y += ws.y * hs0[j] + wn.y * as0[j];
                acc0.z += ws.z * hs0[j] + wn.z * as0[j];
                acc0.w += ws.w * hs0[j] + wn.w * as0[j];
                acc1.x += ws.x * hs1[j] + wn.x * as1[j];
                acc1.y += ws.y * hs1[j] + wn.y * as1[j];
                acc1.z += ws.z * hs1[j] + wn.z * as1[j];
                acc1.w += ws.w * hs1[j] + wn.w * as1[j];
            }
        }
    }

    const float4 bv = *(const float4*)(bias + c4 * 4);
    ushort4 o0, o1;
    o0.x = f2b(fmaxf(acc0.x + bv.x, 0.f)); o0.y = f2b(fmaxf(acc0.y + bv.y, 0.f));
    o0.z = f2b(fmaxf(acc0.z + bv.z, 0.f)); o0.w = f2b(fmaxf(acc0.w + bv.w, 0.f));
    o1.x = f2b(fmaxf(acc1.x + bv.x, 0.f)); o1.y = f2b(fmaxf(acc1.y + bv.y, 0.f));
    o1.z = f2b(fmaxf(acc1.z + bv.z, 0.f)); o1.w = f2b(fmaxf(acc1.w + bv.w, 0.f));
    *(ushort4*)(hout + (size_t)(bbase + n0) * F + c4 * 4) = o0;
    *(ushort4*)(hout + (size_t)(bbase + n1) * F + c4 * 4) = o1;
}

// Final layer: FOUT=16, no relu, f32 output.
__global__ __launch_bounds__(256) void k_layer16(
    const ushort* __restrict__ hin, const int* __restrict__ rowptr,
    const int* __restrict__ deg, const int* __restrict__ col,
    const float* __restrict__ Ws, const float* __restrict__ Wn,
    const float* __restrict__ bias, float* __restrict__ hout) {
    __shared__ float hT[16][F];
    __shared__ float aT[16][F];
    __shared__ float WsT[CLS][132];   // transposed [c][k], padded
    __shared__ float WnT[CLS][132];
    const int tid = threadIdx.x;
    const int bbase = blockIdx.x * 16;

    load_and_aggregate_b(hin, rowptr, deg, col, bbase, hT, aT);

    for (int i = tid; i < F * CLS; i += 256) {
        const int k = i >> 4, c = i & 15;
        WsT[c][k] = Ws[i];
        WnT[c][k] = Wn[i];
    }
    __syncthreads();

    const int c  = tid & 15;
    const int nl = tid >> 4;
    float acc = 0.f;
    #pragma unroll
    for (int kq = 0; kq < 32; ++kq) {
        const float4 h  = *(const float4*)&hT[nl][kq * 4];
        const float4 a  = *(const float4*)&aT[nl][kq * 4];
        const float4 ws = *(const float4*)&WsT[c][kq * 4];
        const float4 wn = *(const float4*)&WnT[c][kq * 4];
        acc += h.x * ws.x + h.y * ws.y + h.z * ws.z + h.w * ws.w;
        acc += a.x * wn.x + a.y * wn.y + a.z * wn.z + a.w * wn.w;
    }
    acc += bias[c];
    hout[(size_t)(bbase + nl) * CLS + c] = acc;
}

// ---------------- edge scoring ----------------

__global__ void k_score(const float* __restrict__ H3,
                        const int* __restrict__ pu, const int* __restrict__ pv,
                        const int* __restrict__ nu, const int* __restrict__ nv,
                        float* __restrict__ out) {
    int i = blockIdx.x * 256 + threadIdx.x;
    if (i >= EPOS + ENEG) return;
    int u, v, o;
    if (i < EPOS) { u = pu[i]; v = pv[i]; o = i; }
    else { int j = i - EPOS; u = nu[j]; v = nv[j]; o = EPOS + j; }
    const float4* a = (const float4*)(H3 + (size_t)u * CLS);
    const float4* b = (const float4*)(H3 + (size_t)v * CLS);
    float s = 0.f;
    #pragma unroll
    for (int r = 0; r < 4; ++r) {
        const float4 av = a[r], bv = b[r];
        s += av.x * bv.x + av.y * bv.y + av.z * bv.z + av.w * bv.w;
    }
    out[o] = s;
}

// ---------------- launch ----------------

extern "C" void kernel_launch(void* const* d_in, const int* in_sizes, int n_in,
                              void* d_out, int out_size, void* d_ws, size_t ws_size,
                              hipStream_t stream) {
    const float* x     = (const float*)d_in[0];
    const int*   src   = (const int*)d_in[1];
    const int*   dst   = (const int*)d_in[2];
    const int*   pos_u = (const int*)d_in[3];
    const int*   pos_v = (const int*)d_in[4];
    const int*   neg_u = (const int*)d_in[5];
    const int*   neg_v = (const int*)d_in[6];
    const float* W1s = (const float*)d_in[7];
    const float* W1n = (const float*)d_in[8];
    const float* b1  = (const float*)d_in[9];
    const float* W2s = (const float*)d_in[10];
    const float* W2n = (const float*)d_in[11];
    const float* b2  = (const float*)d_in[12];
    const float* W3s = (const float*)d_in[13];
    const float* W3n = (const float*)d_in[14];
    const float* b3  = (const float*)d_in[15];
    float* out = (float*)d_out;

    char* ws = (char*)d_ws;
    int*   deg  = (int*)(ws);                                  // NPAD
    int*   rp   = (int*)(ws + (size_t)NPAD * 4);               // NPAD
    int*   cnt  = (int*)(ws + (size_t)NPAD * 8);               // NPAD
    int*   bsum = (int*)(ws + (size_t)NPAD * 12);              // 128
    int*   boff = (int*)(ws + (size_t)NPAD * 12 + 512);        // 128
    int*   col  = (int*)(ws + (size_t)NPAD * 12 + 1024);       // NEDGE
    size_t off = (size_t)NPAD * 12 + 1024 + (size_t)NEDGE * 4;
    off = (off + 255) & ~(size_t)255;
    ushort* Xb = (ushort*)(ws + off); off += (size_t)NNODE * F * 2;
    off = (off + 255) & ~(size_t)255;
    ushort* H1 = (ushort*)(ws + off); off += (size_t)NNODE * F * 2;
    off = (off + 255) & ~(size_t)255;
    ushort* H2 = (ushort*)(ws + off); off += (size_t)NNODE * F * 2;
    off = (off + 255) & ~(size_t)255;
    float*  H3 = (float*)(ws + off);                           // N*CLS f32

    hipMemsetAsync(deg, 0, (size_t)NPAD * 4, stream);
    hipMemsetAsync(cnt, 0, (size_t)NPAD * 4, stream);

    k_cast<<<NNODE * F / 4 / 256, 256, 0, stream>>>(x, Xb);

    k_degree<<<NEDGE / 256, 256, 0, stream>>>(dst, deg);
    k_scan1<<<NB, 256, 0, stream>>>(deg, rp, bsum);
    k_scan2<<<1, 64, 0, stream>>>(bsum, boff);
    k_scan3<<<NPAD / 256, 256, 0, stream>>>(rp, boff);
    k_scatter<<<NEDGE / 256, 256, 0, stream>>>(src, dst, rp, cnt, col);

    k_layer128<<<NNODE / 16, 256, 0, stream>>>(Xb, rp, deg, col, W1s, W1n, b1, H1);
    k_layer128<<<NNODE / 16, 256, 0, stream>>>(H1, rp, deg, col, W2s, W2n, b2, H2);
    k_layer16 <<<NNODE / 16, 256, 0, stream>>>(H2, rp, deg, col, W3s, W3n, b3, H3);

    k_score<<<(EPOS + ENEG + 255) / 256, 256, 0, stream>>>(H3, pos_u, pos_v,
                                                           neg_u, neg_v, out);
}

// Round 3
// 438.953 us; speedup vs baseline: 2.3075x; 1.7974x over previous
//
#include <hip/hip_runtime.h>

static constexpr int NNODE = 100000;
static constexpr int NEDGE = 1600000;
static constexpr int EPOS  = 100000;
static constexpr int ENEG  = 500000;
static constexpr int F     = 128;
static constexpr int CLS   = 16;
static constexpr int NPAD  = 100352;   // 98 * 1024, >= NNODE
static constexpr int NB    = 98;       // scan blocks (1024 elems each)

using bf16x8 = __attribute__((ext_vector_type(8))) short;
using f32x4  = __attribute__((ext_vector_type(4))) float;

// ---------------- bf16 helpers ----------------

__device__ __forceinline__ ushort f2b(float f) {           // f32 -> bf16 RNE
    unsigned u = __float_as_uint(f);
    unsigned r = u + 0x7fffu + ((u >> 16) & 1u);
    return (ushort)(r >> 16);
}
__device__ __forceinline__ float b2f(ushort h) {
    return __uint_as_float(((unsigned)h) << 16);
}

__global__ void k_cast(const float* __restrict__ x, ushort* __restrict__ xb) {
    int i = blockIdx.x * 256 + threadIdx.x;   // one float4 per thread
    float4 v = ((const float4*)x)[i];
    ushort4 o; o.x = f2b(v.x); o.y = f2b(v.y); o.z = f2b(v.z); o.w = f2b(v.w);
    ((ushort4*)xb)[i] = o;
}

// weights f32 [K][C] -> bf16 grouped layout: dst[(k>>3)*C*8 + c*8 + (k&7)]
__global__ void k_wcast(const float* __restrict__ W1s, const float* __restrict__ W1n,
                        const float* __restrict__ W2s, const float* __restrict__ W2n,
                        const float* __restrict__ W3s, const float* __restrict__ W3n,
                        ushort* __restrict__ o1s, ushort* __restrict__ o1n,
                        ushort* __restrict__ o2s, ushort* __restrict__ o2n,
                        ushort* __restrict__ o3s, ushort* __restrict__ o3n) {
    const int b = blockIdx.x;
    const int t = threadIdx.x;
    const float* src; ushort* dst; int C; int idx;
    if      (b < 64)  { src = W1s; dst = o1s; C = 128; idx = b * 256 + t; }
    else if (b < 128) { src = W1n; dst = o1n; C = 128; idx = (b - 64) * 256 + t; }
    else if (b < 192) { src = W2s; dst = o2s; C = 128; idx = (b - 128) * 256 + t; }
    else if (b < 256) { src = W2n; dst = o2n; C = 128; idx = (b - 192) * 256 + t; }
    else if (b < 264) { src = W3s; dst = o3s; C = 16;  idx = (b - 256) * 256 + t; }
    else              { src = W3n; dst = o3n; C = 16;  idx = (b - 264) * 256 + t; }
    const int k = idx / C, c = idx % C;
    dst[(k >> 3) * C * 8 + c * 8 + (k & 7)] = f2b(src[idx]);
}

// ---------------- CSR build ----------------

__global__ void k_degree(const int* __restrict__ dst, int* __restrict__ deg) {
    int e = blockIdx.x * 256 + threadIdx.x;
    if (e < NEDGE) atomicAdd(&deg[dst[e]], 1);
}

__global__ void k_scan1(const int* __restrict__ deg, int* __restrict__ rp,
                        int* __restrict__ bsum) {
    __shared__ int s[256];
    const int t = threadIdx.x;
    const int base = blockIdx.x * 1024 + t * 4;
    const int v0 = deg[base], v1 = deg[base + 1], v2 = deg[base + 2], v3 = deg[base + 3];
    const int tsum = v0 + v1 + v2 + v3;
    s[t] = tsum;
    __syncthreads();
    for (int off = 1; off < 256; off <<= 1) {
        int val = (t >= off) ? s[t - off] : 0;
        __syncthreads();
        s[t] += val;
        __syncthreads();
    }
    const int excl = s[t] - tsum;
    rp[base]     = excl;
    rp[base + 1] = excl + v0;
    rp[base + 2] = excl + v0 + v1;
    rp[base + 3] = excl + v0 + v1 + v2;
    if (t == 255) bsum[blockIdx.x] = s[255];
}

__global__ void k_scan2(const int* __restrict__ bsum, int* __restrict__ boff) {
    if (threadIdx.x == 0 && blockIdx.x == 0) {
        int run = 0;
        for (int b = 0; b < NB; ++b) { boff[b] = run; run += bsum[b]; }
    }
}

__global__ void k_scan3(int* __restrict__ rp, const int* __restrict__ boff) {
    int i = blockIdx.x * 256 + threadIdx.x;   // i < NPAD
    rp[i] += boff[i >> 10];
}

__global__ void k_scatter(const int* __restrict__ src, const int* __restrict__ dst,
                          const int* __restrict__ rp, int* __restrict__ cnt,
                          int* __restrict__ col) {
    int e = blockIdx.x * 256 + threadIdx.x;
    if (e < NEDGE) {
        const int d = dst[e];
        const int p = rp[d] + atomicAdd(&cnt[d], 1);
        col[p] = src[e];
    }
}

// ---------------- aggregation: mean of neighbor rows (bf16 -> bf16) ----------------

__global__ __launch_bounds__(256) void k_agg(
    const ushort* __restrict__ hin, const int* __restrict__ rp,
    const int* __restrict__ deg, const int* __restrict__ col,
    ushort* __restrict__ agg) {
    const int tid = threadIdx.x;
    const int row = blockIdx.x * 16 + (tid >> 4);   // 16 rows/block, 16 lanes/row
    const int l16 = tid & 15;
    const int p0 = rp[row];
    const int d  = deg[row];
    const int pe = p0 + d;
    float s0[8] = {0, 0, 0, 0, 0, 0, 0, 0};
    float s1[8] = {0, 0, 0, 0, 0, 0, 0, 0};
    int p = p0;
    for (; p + 2 <= pe; p += 2) {
        const int u0 = col[p];
        const int u1 = col[p + 1];
        const bf16x8 a = *(const bf16x8*)(hin + (size_t)u0 * F + l16 * 8);
        const bf16x8 b = *(const bf16x8*)(hin + (size_t)u1 * F + l16 * 8);
        #pragma unroll
        for (int j = 0; j < 8; ++j) s0[j] += b2f((ushort)a[j]);
        #pragma unroll
        for (int j = 0; j < 8; ++j) s1[j] += b2f((ushort)b[j]);
    }
    if (p < pe) {
        const bf16x8 a = *(const bf16x8*)(hin + (size_t)col[p] * F + l16 * 8);
        #pragma unroll
        for (int j = 0; j < 8; ++j) s0[j] += b2f((ushort)a[j]);
    }
    const float inv = d > 0 ? 1.0f / (float)d : 0.0f;
    bf16x8 o;
    #pragma unroll
    for (int j = 0; j < 8; ++j) o[j] = (short)f2b((s0[j] + s1[j]) * inv);
    *(bf16x8*)(agg + (size_t)row * F + l16 * 8) = o;
}

// ---------------- MFMA GEMM: out = relu(A1@Ws + A2@Wn + b), N=128 ----------------

__global__ __launch_bounds__(256) void k_gemm128(
    const ushort* __restrict__ A1, const ushort* __restrict__ A2,
    const ushort* __restrict__ Ws2, const ushort* __restrict__ Wn2,
    const float* __restrict__ bias, ushort* __restrict__ outb) {
    __shared__ ushort Wl[16384];                 // 32 KB: one weight matrix
    const int tid  = threadIdx.x;
    const int wv   = tid >> 6;
    const int lane = tid & 63;
    const int l16  = lane & 15;
    const int lk   = lane >> 4;
    const int rbase = blockIdx.x * 128 + wv * 32;

    f32x4 acc0[8], acc1[8];
    #pragma unroll
    for (int n = 0; n < 8; ++n) { acc0[n] = (f32x4){0,0,0,0}; acc1[n] = (f32x4){0,0,0,0}; }

    const int r0 = rbase + l16       < NNODE ? rbase + l16       : NNODE - 1;
    const int r1 = rbase + 16 + l16  < NNODE ? rbase + 16 + l16  : NNODE - 1;
    const size_t ra0 = (size_t)r0 * F + lk * 8;
    const size_t ra1 = (size_t)r1 * F + lk * 8;

    #pragma unroll
    for (int mat = 0; mat < 2; ++mat) {
        const ushort* W2 = mat ? Wn2 : Ws2;
        const ushort* A  = mat ? A2  : A1;
        __syncthreads();
        #pragma unroll
        for (int i = 0; i < 8; ++i)
            *(bf16x8*)&Wl[tid * 8 + i * 2048] = *(const bf16x8*)&W2[tid * 8 + i * 2048];
        __syncthreads();
        #pragma unroll
        for (int kb = 0; kb < 4; ++kb) {
            const bf16x8 a0 = *(const bf16x8*)(A + ra0 + kb * 32);
            const bf16x8 a1 = *(const bf16x8*)(A + ra1 + kb * 32);
            const int kg = kb * 4 + lk;
            #pragma unroll
            for (int n = 0; n < 8; ++n) {
                const bf16x8 b = *(const bf16x8*)&Wl[kg * 1024 + (n * 16 + l16) * 8];
                acc0[n] = __builtin_amdgcn_mfma_f32_16x16x32_bf16(a0, b, acc0[n], 0, 0, 0);
                acc1[n] = __builtin_amdgcn_mfma_f32_16x16x32_bf16(a1, b, acc1[n], 0, 0, 0);
            }
        }
    }

    #pragma unroll
    for (int n = 0; n < 8; ++n) {
        const int c = n * 16 + l16;
        const float bv = bias[c];
        #pragma unroll
        for (int j = 0; j < 4; ++j) {
            const int rr0 = rbase + lk * 4 + j;
            const int rr1 = rbase + 16 + lk * 4 + j;
            if (rr0 < NNODE) outb[(size_t)rr0 * F + c] = f2b(fmaxf(acc0[n][j] + bv, 0.f));
            if (rr1 < NNODE) outb[(size_t)rr1 * F + c] = f2b(fmaxf(acc1[n][j] + bv, 0.f));
        }
    }
}

// ---------------- MFMA GEMM: out = A1@Ws + A2@Wn + b, N=16, f32 out ----------------

__global__ __launch_bounds__(256) void k_gemm16(
    const ushort* __restrict__ A1, const ushort* __restrict__ A2,
    const ushort* __restrict__ Ws2, const ushort* __restrict__ Wn2,
    const float* __restrict__ bias, float* __restrict__ out) {
    __shared__ ushort Wl[2][2048];               // 4 KB each
    const int tid  = threadIdx.x;
    const int wv   = tid >> 6;
    const int lane = tid & 63;
    const int l16  = lane & 15;
    const int lk   = lane >> 4;
    const int rbase = blockIdx.x * 256 + wv * 64;

    *(bf16x8*)&Wl[0][tid * 8] = *(const bf16x8*)&Ws2[tid * 8];
    *(bf16x8*)&Wl[1][tid * 8] = *(const bf16x8*)&Wn2[tid * 8];
    __syncthreads();

    f32x4 acc[4];
    #pragma unroll
    for (int rt = 0; rt < 4; ++rt) acc[rt] = (f32x4){0,0,0,0};

    #pragma unroll
    for (int mat = 0; mat < 2; ++mat) {
        const ushort* A = mat ? A2 : A1;
        #pragma unroll
        for (int kb = 0; kb < 4; ++kb) {
            const int kg = kb * 4 + lk;
            const bf16x8 b = *(const bf16x8*)&Wl[mat][kg * 128 + l16 * 8];
            #pragma unroll
            for (int rt = 0; rt < 4; ++rt) {
                int row = rbase + rt * 16 + l16;
                if (row >= NNODE) row = NNODE - 1;
                const bf16x8 a = *(const bf16x8*)(A + (size_t)row * F + kb * 32 + lk * 8);
                acc[rt] = __builtin_amdgcn_mfma_f32_16x16x32_bf16(a, b, acc[rt], 0, 0, 0);
            }
        }
    }

    const float bv = bias[l16];
    #pragma unroll
    for (int rt = 0; rt < 4; ++rt) {
        #pragma unroll
        for (int j = 0; j < 4; ++j) {
            const int rr = rbase + rt * 16 + lk * 4 + j;
            if (rr < NNODE) out[(size_t)rr * CLS + l16] = acc[rt][j] + bv;
        }
    }
}

// ---------------- edge scoring ----------------

__global__ void k_score(const float* __restrict__ H3,
                        const int* __restrict__ pu, const int* __restrict__ pv,
                        const int* __restrict__ nu, const int* __restrict__ nv,
                        float* __restrict__ out) {
    int i = blockIdx.x * 256 + threadIdx.x;
    if (i >= EPOS + ENEG) return;
    int u, v, o;
    if (i < EPOS) { u = pu[i]; v = pv[i]; o = i; }
    else { int j = i - EPOS; u = nu[j]; v = nv[j]; o = EPOS + j; }
    const float4* a = (const float4*)(H3 + (size_t)u * CLS);
    const float4* b = (const float4*)(H3 + (size_t)v * CLS);
    float s = 0.f;
    #pragma unroll
    for (int r = 0; r < 4; ++r) {
        const float4 av = a[r], bv = b[r];
        s += av.x * bv.x + av.y * bv.y + av.z * bv.z + av.w * bv.w;
    }
    out[o] = s;
}

// ---------------- launch ----------------

extern "C" void kernel_launch(void* const* d_in, const int* in_sizes, int n_in,
                              void* d_out, int out_size, void* d_ws, size_t ws_size,
                              hipStream_t stream) {
    const float* x     = (const float*)d_in[0];
    const int*   src   = (const int*)d_in[1];
    const int*   dst   = (const int*)d_in[2];
    const int*   pos_u = (const int*)d_in[3];
    const int*   pos_v = (const int*)d_in[4];
    const int*   neg_u = (const int*)d_in[5];
    const int*   neg_v = (const int*)d_in[6];
    const float* W1s = (const float*)d_in[7];
    const float* W1n = (const float*)d_in[8];
    const float* b1  = (const float*)d_in[9];
    const float* W2s = (const float*)d_in[10];
    const float* W2n = (const float*)d_in[11];
    const float* b2  = (const float*)d_in[12];
    const float* W3s = (const float*)d_in[13];
    const float* W3n = (const float*)d_in[14];
    const float* b3  = (const float*)d_in[15];
    float* out = (float*)d_out;

    char* ws = (char*)d_ws;
    int*   deg  = (int*)(ws);                                  // NPAD
    int*   rp   = (int*)(ws + (size_t)NPAD * 4);               // NPAD
    int*   cnt  = (int*)(ws + (size_t)NPAD * 8);               // NPAD
    int*   bsum = (int*)(ws + (size_t)NPAD * 12);              // 128
    int*   boff = (int*)(ws + (size_t)NPAD * 12 + 512);        // 128
    int*   col  = (int*)(ws + (size_t)NPAD * 12 + 1024);       // NEDGE
    size_t off = (size_t)NPAD * 12 + 1024 + (size_t)NEDGE * 4;
    off = (off + 255) & ~(size_t)255;
    ushort* Xb  = (ushort*)(ws + off); off += (size_t)NNODE * F * 2;
    off = (off + 255) & ~(size_t)255;
    ushort* H1  = (ushort*)(ws + off); off += (size_t)NNODE * F * 2;
    off = (off + 255) & ~(size_t)255;
    ushort* H2  = (ushort*)(ws + off); off += (size_t)NNODE * F * 2;
    off = (off + 255) & ~(size_t)255;
    ushort* Agg = (ushort*)(ws + off); off += (size_t)NNODE * F * 2;
    off = (off + 255) & ~(size_t)255;
    float*  H3  = (float*)(ws + off);  off += (size_t)NNODE * CLS * 4;
    off = (off + 255) & ~(size_t)255;
    ushort* Wb1s = (ushort*)(ws + off); off += 16384 * 2;
    ushort* Wb1n = (ushort*)(ws + off); off += 16384 * 2;
    ushort* Wb2s = (ushort*)(ws + off); off += 16384 * 2;
    ushort* Wb2n = (ushort*)(ws + off); off += 16384 * 2;
    ushort* Wb3s = (ushort*)(ws + off); off += 2048 * 2;
    ushort* Wb3n = (ushort*)(ws + off); off += 2048 * 2;

    hipMemsetAsync(deg, 0, (size_t)NPAD * 4, stream);
    hipMemsetAsync(cnt, 0, (size_t)NPAD * 4, stream);

    k_cast<<<NNODE * F / 4 / 256, 256, 0, stream>>>(x, Xb);
    k_wcast<<<272, 256, 0, stream>>>(W1s, W1n, W2s, W2n, W3s, W3n,
                                     Wb1s, Wb1n, Wb2s, Wb2n, Wb3s, Wb3n);

    k_degree<<<NEDGE / 256, 256, 0, stream>>>(dst, deg);
    k_scan1<<<NB, 256, 0, stream>>>(deg, rp, bsum);
    k_scan2<<<1, 64, 0, stream>>>(bsum, boff);
    k_scan3<<<NPAD / 256, 256, 0, stream>>>(rp, boff);
    k_scatter<<<NEDGE / 256, 256, 0, stream>>>(src, dst, rp, cnt, col);

    k_agg<<<NNODE / 16, 256, 0, stream>>>(Xb, rp, deg, col, Agg);
    k_gemm128<<<(NNODE + 127) / 128, 256, 0, stream>>>(Xb, Agg, Wb1s, Wb1n, b1, H1);

    k_agg<<<NNODE / 16, 256, 0, stream>>>(H1, rp, deg, col, Agg);
    k_gemm128<<<(NNODE + 127) / 128, 256, 0, stream>>>(H1, Agg, Wb2s, Wb2n, b2, H2);

    k_agg<<<NNODE / 16, 256, 0, stream>>>(H2, rp, deg, col, Agg);
    k_gemm16<<<(NNODE + 255) / 256, 256, 0, stream>>>(H2, Agg, Wb3s, Wb3n, b3, H3);

    k_score<<<(EPOS + ENEG + 255) / 256, 256, 0, stream>>>(H3, pos_u, pos_v,
                                                           neg_u, neg_v, out);
}

// Round 4
// 318.759 us; speedup vs baseline: 3.1776x; 1.3771x over previous
//
#include <hip/hip_runtime.h>

static constexpr int NNODE = 100000;
static constexpr int NEDGE = 1600000;
static constexpr int EPOS  = 100000;
static constexpr int ENEG  = 500000;
static constexpr int F     = 128;
static constexpr int CLS   = 16;
static constexpr int NPAD  = 100352;   // 196 * 512
static constexpr int NBKT  = 196;      // buckets of 512 nodes (dst >> 9)
static constexpr int BCAP  = 10240;    // bucket capacity (mean 8192, 22 sigma margin)
static constexpr int TILE  = 8192;     // edges per k_bin block

using bf16x8 = __attribute__((ext_vector_type(8))) short;
using f32x4  = __attribute__((ext_vector_type(4))) float;

// ---------------- bf16 helpers ----------------

__device__ __forceinline__ ushort f2b(float f) {           // f32 -> bf16 RNE
    unsigned u = __float_as_uint(f);
    unsigned r = u + 0x7fffu + ((u >> 16) & 1u);
    return (ushort)(r >> 16);
}
__device__ __forceinline__ float b2f(ushort h) {
    return __uint_as_float(((unsigned)h) << 16);
}

__global__ void k_cast(const float* __restrict__ x, ushort* __restrict__ xb) {
    int i = blockIdx.x * 256 + threadIdx.x;   // one float4 per thread
    float4 v = ((const float4*)x)[i];
    ushort4 o; o.x = f2b(v.x); o.y = f2b(v.y); o.z = f2b(v.z); o.w = f2b(v.w);
    ((ushort4*)xb)[i] = o;
}

// weights f32 [K][C] -> bf16 grouped layout: dst[(k>>3)*C*8 + c*8 + (k&7)]
__global__ void k_wcast(const float* __restrict__ W1s, const float* __restrict__ W1n,
                        const float* __restrict__ W2s, const float* __restrict__ W2n,
                        const float* __restrict__ W3s, const float* __restrict__ W3n,
                        ushort* __restrict__ o1s, ushort* __restrict__ o1n,
                        ushort* __restrict__ o2s, ushort* __restrict__ o2n,
                        ushort* __restrict__ o3s, ushort* __restrict__ o3n) {
    const int b = blockIdx.x;
    const int t = threadIdx.x;
    const float* src; ushort* dst; int C; int idx;
    if      (b < 64)  { src = W1s; dst = o1s; C = 128; idx = b * 256 + t; }
    else if (b < 128) { src = W1n; dst = o1n; C = 128; idx = (b - 64) * 256 + t; }
    else if (b < 192) { src = W2s; dst = o2s; C = 128; idx = (b - 128) * 256 + t; }
    else if (b < 256) { src = W2n; dst = o2n; C = 128; idx = (b - 192) * 256 + t; }
    else if (b < 264) { src = W3s; dst = o3s; C = 16;  idx = (b - 256) * 256 + t; }
    else              { src = W3n; dst = o3n; C = 16;  idx = (b - 264) * 256 + t; }
    const int k = idx / C, c = idx % C;
    dst[(k >> 3) * C * 8 + c * 8 + (k & 7)] = f2b(src[idx]);
}

// ---------------- CSR build: bucket binning (phase 1) ----------------
// Packs edge as src | (dst&511)<<17, writes bucket-run-contiguous chunks.

__global__ __launch_bounds__(256) void k_bin(
    const int* __restrict__ src, const int* __restrict__ dst,
    uint* __restrict__ bins, int* __restrict__ gcount) {
    __shared__ int hist[256];
    __shared__ int lofs[256];
    __shared__ int gbase[256];
    __shared__ int run[256];
    __shared__ uint stage[TILE];
    const int tid = threadIdx.x;
    const int e0  = blockIdx.x * TILE;

    hist[tid] = 0;
    __syncthreads();
    #pragma unroll
    for (int j = 0; j < TILE / 256; ++j) {
        const int e = e0 + j * 256 + tid;
        if (e < NEDGE) atomicAdd(&hist[dst[e] >> 9], 1);
    }
    __syncthreads();
    const int x = hist[tid];
    lofs[tid] = x;
    __syncthreads();
    for (int off = 1; off < 256; off <<= 1) {
        int y = (tid >= off) ? lofs[tid - off] : 0;
        __syncthreads();
        lofs[tid] += y;
        __syncthreads();
    }
    const int excl = lofs[tid] - x;
    __syncthreads();
    lofs[tid]  = excl;
    run[tid]   = excl;
    gbase[tid] = (x > 0) ? atomicAdd(&gcount[tid], x) : 0;
    __syncthreads();
    #pragma unroll
    for (int j = 0; j < TILE / 256; ++j) {
        const int e = e0 + j * 256 + tid;
        if (e < NEDGE) {
            const int d = dst[e];
            const int b = d >> 9;
            const int r = atomicAdd(&run[b], 1);
            stage[r] = (uint)(src[e] | ((d & 511) << 17));
        }
    }
    __syncthreads();
    const int total = lofs[255] + hist[255];
    for (int i = tid; i < total; i += 256) {
        int lo = 0, hi = 255;                       // largest b with lofs[b] <= i
        while (lo < hi) {
            const int mid = (lo + hi + 1) >> 1;
            if (lofs[mid] <= i) lo = mid; else hi = mid - 1;
        }
        bins[(size_t)lo * BCAP + gbase[lo] + (i - lofs[lo])] = stage[i];
    }
}

// exclusive scan of gcount[256] -> ebase[256]
__global__ void k_bscan(const int* __restrict__ gcount, int* __restrict__ ebase) {
    __shared__ int s[256];
    const int t = threadIdx.x;
    const int x = gcount[t];
    s[t] = x;
    __syncthreads();
    for (int off = 1; off < 256; off <<= 1) {
        int y = (t >= off) ? s[t - off] : 0;
        __syncthreads();
        s[t] += y;
        __syncthreads();
    }
    ebase[t] = s[t] - x;
}

// ---------------- CSR build: per-bucket degree/scan/scatter (phase 2) ----------------

__global__ __launch_bounds__(256) void k_build(
    const uint* __restrict__ bins, const int* __restrict__ gcount,
    const int* __restrict__ ebase, int* __restrict__ rp, int* __restrict__ col) {
    __shared__ int ldeg[512];
    __shared__ int lrp[512];
    __shared__ int tmp[256];
    const int tid = threadIdx.x;
    const int b   = blockIdx.x;
    const int nbase = b * 512;
    const int cnt   = gcount[b];
    const int eb    = ebase[b];
    const uint* mybins = bins + (size_t)b * BCAP;

    ldeg[tid] = 0; ldeg[tid + 256] = 0;
    __syncthreads();
    for (int i = tid; i < cnt; i += 256)
        atomicAdd(&ldeg[(mybins[i] >> 17) & 511], 1);
    __syncthreads();
    const int a0 = ldeg[2 * tid], a1 = ldeg[2 * tid + 1];
    tmp[tid] = a0 + a1;
    __syncthreads();
    for (int off = 1; off < 256; off <<= 1) {
        int y = (tid >= off) ? tmp[tid - off] : 0;
        __syncthreads();
        tmp[tid] += y;
        __syncthreads();
    }
    const int pbase = tid ? tmp[tid - 1] : 0;
    lrp[2 * tid]     = pbase;
    lrp[2 * tid + 1] = pbase + a0;
    __syncthreads();
    rp[nbase + tid]       = eb + lrp[tid];
    rp[nbase + tid + 256] = eb + lrp[tid + 256];
    ldeg[tid] = lrp[tid]; ldeg[tid + 256] = lrp[tid + 256];   // running counters
    __syncthreads();
    for (int i = tid; i < cnt; i += 256) {
        const uint v = mybins[i];
        const int dlow = (v >> 17) & 511;
        const int p = atomicAdd(&ldeg[dlow], 1);
        col[eb + p] = (int)(v & 0x1FFFF);
    }
}

// ---------------- aggregation: mean of neighbor rows (bf16 -> bf16), width 128 ----------------

__global__ __launch_bounds__(256) void k_agg(
    const ushort* __restrict__ hin, const int* __restrict__ rp,
    const int* __restrict__ col, ushort* __restrict__ agg) {
    const int tid = threadIdx.x;
    const int row = blockIdx.x * 16 + (tid >> 4);   // 16 rows/block, 16 lanes/row
    const int l16 = tid & 15;
    const int p0 = rp[row];
    const int pe = rp[row + 1];
    const int d  = pe - p0;
    float s0[8] = {0, 0, 0, 0, 0, 0, 0, 0};
    float s1[8] = {0, 0, 0, 0, 0, 0, 0, 0};
    int p = p0;
    for (; p + 2 <= pe; p += 2) {
        const int u0 = col[p];
        const int u1 = col[p + 1];
        const bf16x8 a = *(const bf16x8*)(hin + (size_t)u0 * F + l16 * 8);
        const bf16x8 b = *(const bf16x8*)(hin + (size_t)u1 * F + l16 * 8);
        #pragma unroll
        for (int j = 0; j < 8; ++j) s0[j] += b2f((ushort)a[j]);
        #pragma unroll
        for (int j = 0; j < 8; ++j) s1[j] += b2f((ushort)b[j]);
    }
    if (p < pe) {
        const bf16x8 a = *(const bf16x8*)(hin + (size_t)col[p] * F + l16 * 8);
        #pragma unroll
        for (int j = 0; j < 8; ++j) s0[j] += b2f((ushort)a[j]);
    }
    const float inv = d > 0 ? 1.0f / (float)d : 0.0f;
    bf16x8 o;
    #pragma unroll
    for (int j = 0; j < 8; ++j) o[j] = (short)f2b((s0[j] + s1[j]) * inv);
    *(bf16x8*)(agg + (size_t)row * F + l16 * 8) = o;
}

// width-16 aggregation (for G3): 2 lanes/row, 128 rows/block
__global__ __launch_bounds__(256) void k_agg16(
    const ushort* __restrict__ G, const int* __restrict__ rp,
    const int* __restrict__ col, ushort* __restrict__ aggg) {
    const int tid  = threadIdx.x;
    const int row  = blockIdx.x * 128 + (tid >> 1);
    const int half = tid & 1;
    if (row >= NNODE) return;
    const int p0 = rp[row];
    const int pe = rp[row + 1];
    const int d  = pe - p0;
    float s0[8] = {0, 0, 0, 0, 0, 0, 0, 0};
    float s1[8] = {0, 0, 0, 0, 0, 0, 0, 0};
    int p = p0;
    for (; p + 2 <= pe; p += 2) {
        const int u0 = col[p];
        const int u1 = col[p + 1];
        const bf16x8 a = *(const bf16x8*)(G + (size_t)u0 * CLS + half * 8);
        const bf16x8 b = *(const bf16x8*)(G + (size_t)u1 * CLS + half * 8);
        #pragma unroll
        for (int j = 0; j < 8; ++j) s0[j] += b2f((ushort)a[j]);
        #pragma unroll
        for (int j = 0; j < 8; ++j) s1[j] += b2f((ushort)b[j]);
    }
    if (p < pe) {
        const bf16x8 a = *(const bf16x8*)(G + (size_t)col[p] * CLS + half * 8);
        #pragma unroll
        for (int j = 0; j < 8; ++j) s0[j] += b2f((ushort)a[j]);
    }
    const float inv = d > 0 ? 1.0f / (float)d : 0.0f;
    bf16x8 o;
    #pragma unroll
    for (int j = 0; j < 8; ++j) o[j] = (short)f2b((s0[j] + s1[j]) * inv);
    *(bf16x8*)(aggg + (size_t)row * CLS + half * 8) = o;
}

// ---------------- MFMA GEMM: out = relu(A1@Ws + A2@Wn + b), N=128 ----------------

__global__ __launch_bounds__(256) void k_gemm128(
    const ushort* __restrict__ A1, const ushort* __restrict__ A2,
    const ushort* __restrict__ Ws2, const ushort* __restrict__ Wn2,
    const float* __restrict__ bias, ushort* __restrict__ outb) {
    __shared__ ushort Wl[16384];                 // 32 KB: one weight matrix
    const int tid  = threadIdx.x;
    const int wv   = tid >> 6;
    const int lane = tid & 63;
    const int l16  = lane & 15;
    const int lk   = lane >> 4;
    const int rbase = blockIdx.x * 128 + wv * 32;

    f32x4 acc0[8], acc1[8];
    #pragma unroll
    for (int n = 0; n < 8; ++n) { acc0[n] = (f32x4){0,0,0,0}; acc1[n] = (f32x4){0,0,0,0}; }

    const int r0 = rbase + l16       < NNODE ? rbase + l16       : NNODE - 1;
    const int r1 = rbase + 16 + l16  < NNODE ? rbase + 16 + l16  : NNODE - 1;
    const size_t ra0 = (size_t)r0 * F + lk * 8;
    const size_t ra1 = (size_t)r1 * F + lk * 8;

    #pragma unroll
    for (int mat = 0; mat < 2; ++mat) {
        const ushort* W2 = mat ? Wn2 : Ws2;
        const ushort* A  = mat ? A2  : A1;
        __syncthreads();
        #pragma unroll
        for (int i = 0; i < 8; ++i)
            *(bf16x8*)&Wl[tid * 8 + i * 2048] = *(const bf16x8*)&W2[tid * 8 + i * 2048];
        __syncthreads();
        #pragma unroll
        for (int kb = 0; kb < 4; ++kb) {
            const bf16x8 a0 = *(const bf16x8*)(A + ra0 + kb * 32);
            const bf16x8 a1 = *(const bf16x8*)(A + ra1 + kb * 32);
            const int kg = kb * 4 + lk;
            #pragma unroll
            for (int n = 0; n < 8; ++n) {
                const bf16x8 b = *(const bf16x8*)&Wl[kg * 1024 + (n * 16 + l16) * 8];
                acc0[n] = __builtin_amdgcn_mfma_f32_16x16x32_bf16(a0, b, acc0[n], 0, 0, 0);
                acc1[n] = __builtin_amdgcn_mfma_f32_16x16x32_bf16(a1, b, acc1[n], 0, 0, 0);
            }
        }
    }

    #pragma unroll
    for (int n = 0; n < 8; ++n) {
        const int c = n * 16 + l16;
        const float bv = bias[c];
        #pragma unroll
        for (int j = 0; j < 4; ++j) {
            const int rr0 = rbase + lk * 4 + j;
            const int rr1 = rbase + 16 + lk * 4 + j;
            if (rr0 < NNODE) outb[(size_t)rr0 * F + c] = f2b(fmaxf(acc0[n][j] + bv, 0.f));
            if (rr1 < NNODE) outb[(size_t)rr1 * F + c] = f2b(fmaxf(acc1[n][j] + bv, 0.f));
        }
    }
}

// ---------------- MFMA GEMM: G = A@W2 (bf16 out, no bias), N=16 ----------------

__global__ __launch_bounds__(256) void k_gemmN16(
    const ushort* __restrict__ A, const ushort* __restrict__ W2,
    ushort* __restrict__ G) {
    __shared__ ushort Wl[2048];
    const int tid  = threadIdx.x;
    const int wv   = tid >> 6;
    const int lane = tid & 63;
    const int l16  = lane & 15;
    const int lk   = lane >> 4;
    const int rbase = blockIdx.x * 256 + wv * 64;

    *(bf16x8*)&Wl[tid * 8] = *(const bf16x8*)&W2[tid * 8];
    __syncthreads();

    f32x4 acc[4];
    #pragma unroll
    for (int rt = 0; rt < 4; ++rt) acc[rt] = (f32x4){0,0,0,0};

    #pragma unroll
    for (int kb = 0; kb < 4; ++kb) {
        const int kg = kb * 4 + lk;
        const bf16x8 b = *(const bf16x8*)&Wl[kg * 128 + l16 * 8];
        #pragma unroll
        for (int rt = 0; rt < 4; ++rt) {
            int row = rbase + rt * 16 + l16;
            if (row >= NNODE) row = NNODE - 1;
            const bf16x8 a = *(const bf16x8*)(A + (size_t)row * F + kb * 32 + lk * 8);
            acc[rt] = __builtin_amdgcn_mfma_f32_16x16x32_bf16(a, b, acc[rt], 0, 0, 0);
        }
    }

    #pragma unroll
    for (int rt = 0; rt < 4; ++rt) {
        #pragma unroll
        for (int j = 0; j < 4; ++j) {
            const int rr = rbase + rt * 16 + lk * 4 + j;
            if (rr < NNODE) G[(size_t)rr * CLS + l16] = f2b(acc[rt][j]);
        }
    }
}

// ---------------- final: H3 = A@Ws + AggG + b (f32 out), N=16 ----------------

__global__ __launch_bounds__(256) void k_gemm16s(
    const ushort* __restrict__ A, const ushort* __restrict__ Ws2,
    const ushort* __restrict__ aggg, const float* __restrict__ bias,
    float* __restrict__ out) {
    __shared__ ushort Wl[2048];
    const int tid  = threadIdx.x;
    const int wv   = tid >> 6;
    const int lane = tid & 63;
    const int l16  = lane & 15;
    const int lk   = lane >> 4;
    const int rbase = blockIdx.x * 256 + wv * 64;

    *(bf16x8*)&Wl[tid * 8] = *(const bf16x8*)&Ws2[tid * 8];
    __syncthreads();

    f32x4 acc[4];
    #pragma unroll
    for (int rt = 0; rt < 4; ++rt) acc[rt] = (f32x4){0,0,0,0};

    #pragma unroll
    for (int kb = 0; kb < 4; ++kb) {
        const int kg = kb * 4 + lk;
        const bf16x8 b = *(const bf16x8*)&Wl[kg * 128 + l16 * 8];
        #pragma unroll
        for (int rt = 0; rt < 4; ++rt) {
            int row = rbase + rt * 16 + l16;
            if (row >= NNODE) row = NNODE - 1;
            const bf16x8 a = *(const bf16x8*)(A + (size_t)row * F + kb * 32 + lk * 8);
            acc[rt] = __builtin_amdgcn_mfma_f32_16x16x32_bf16(a, b, acc[rt], 0, 0, 0);
        }
    }

    const float bv = bias[l16];
    #pragma unroll
    for (int rt = 0; rt < 4; ++rt) {
        #pragma unroll
        for (int j = 0; j < 4; ++j) {
            const int rr = rbase + rt * 16 + lk * 4 + j;
            if (rr < NNODE)
                out[(size_t)rr * CLS + l16] =
                    acc[rt][j] + b2f(aggg[(size_t)rr * CLS + l16]) + bv;
        }
    }
}

// ---------------- edge scoring ----------------

__global__ void k_score(const float* __restrict__ H3,
                        const int* __restrict__ pu, const int* __restrict__ pv,
                        const int* __restrict__ nu, const int* __restrict__ nv,
                        float* __restrict__ out) {
    int i = blockIdx.x * 256 + threadIdx.x;
    if (i >= EPOS + ENEG) return;
    int u, v, o;
    if (i < EPOS) { u = pu[i]; v = pv[i]; o = i; }
    else { int j = i - EPOS; u = nu[j]; v = nv[j]; o = EPOS + j; }
    const float4* a = (const float4*)(H3 + (size_t)u * CLS);
    const float4* b = (const float4*)(H3 + (size_t)v * CLS);
    float s = 0.f;
    #pragma unroll
    for (int r = 0; r < 4; ++r) {
        const float4 av = a[r], bv = b[r];
        s += av.x * bv.x + av.y * bv.y + av.z * bv.z + av.w * bv.w;
    }
    out[o] = s;
}

// ---------------- launch ----------------

extern "C" void kernel_launch(void* const* d_in, const int* in_sizes, int n_in,
                              void* d_out, int out_size, void* d_ws, size_t ws_size,
                              hipStream_t stream) {
    const float* x     = (const float*)d_in[0];
    const int*   src   = (const int*)d_in[1];
    const int*   dst   = (const int*)d_in[2];
    const int*   pos_u = (const int*)d_in[3];
    const int*   pos_v = (const int*)d_in[4];
    const int*   neg_u = (const int*)d_in[5];
    const int*   neg_v = (const int*)d_in[6];
    const float* W1s = (const float*)d_in[7];
    const float* W1n = (const float*)d_in[8];
    const float* b1  = (const float*)d_in[9];
    const float* W2s = (const float*)d_in[10];
    const float* W2n = (const float*)d_in[11];
    const float* b2  = (const float*)d_in[12];
    const float* W3s = (const float*)d_in[13];
    const float* W3n = (const float*)d_in[14];
    const float* b3  = (const float*)d_in[15];
    float* out = (float*)d_out;

    char* ws = (char*)d_ws;
    size_t off = 0;
    int* rp     = (int*)(ws + off); off += (size_t)(NPAD + 256) * 4;
    int* gcount = (int*)(ws + off); off += 256 * 4;
    int* ebase  = (int*)(ws + off); off += 256 * 4;
    off = (off + 255) & ~(size_t)255;
    uint* bins  = (uint*)(ws + off); off += (size_t)NBKT * BCAP * 4;
    int*  col   = (int*)(ws + off);  off += (size_t)NEDGE * 4;
    off = (off + 255) & ~(size_t)255;
    ushort* Xb   = (ushort*)(ws + off); off += (size_t)NNODE * F * 2;
    off = (off + 255) & ~(size_t)255;
    ushort* H1   = (ushort*)(ws + off); off += (size_t)NNODE * F * 2;
    off = (off + 255) & ~(size_t)255;
    ushort* H2   = (ushort*)(ws + off); off += (size_t)NNODE * F * 2;
    off = (off + 255) & ~(size_t)255;
    ushort* Agg  = (ushort*)(ws + off); off += (size_t)NNODE * F * 2;
    off = (off + 255) & ~(size_t)255;
    ushort* G3   = (ushort*)(ws + off); off += (size_t)NNODE * CLS * 2;
    off = (off + 255) & ~(size_t)255;
    ushort* AggG = (ushort*)(ws + off); off += (size_t)NNODE * CLS * 2;
    off = (off + 255) & ~(size_t)255;
    float*  H3   = (float*)(ws + off);  off += (size_t)NNODE * CLS * 4;
    off = (off + 255) & ~(size_t)255;
    ushort* Wb1s = (ushort*)(ws + off); off += 16384 * 2;
    ushort* Wb1n = (ushort*)(ws + off); off += 16384 * 2;
    ushort* Wb2s = (ushort*)(ws + off); off += 16384 * 2;
    ushort* Wb2n = (ushort*)(ws + off); off += 16384 * 2;
    ushort* Wb3s = (ushort*)(ws + off); off += 2048 * 2;
    ushort* Wb3n = (ushort*)(ws + off); off += 2048 * 2;

    hipMemsetAsync(gcount, 0, 256 * 4, stream);

    k_cast<<<NNODE * F / 4 / 256, 256, 0, stream>>>(x, Xb);
    k_wcast<<<272, 256, 0, stream>>>(W1s, W1n, W2s, W2n, W3s, W3n,
                                     Wb1s, Wb1n, Wb2s, Wb2n, Wb3s, Wb3n);

    k_bin<<<(NEDGE + TILE - 1) / TILE, 256, 0, stream>>>(src, dst, bins, gcount);
    k_bscan<<<1, 256, 0, stream>>>(gcount, ebase);
    k_build<<<NBKT, 256, 0, stream>>>(bins, gcount, ebase, rp, col);

    k_agg<<<NNODE / 16, 256, 0, stream>>>(Xb, rp, col, Agg);
    k_gemm128<<<(NNODE + 127) / 128, 256, 0, stream>>>(Xb, Agg, Wb1s, Wb1n, b1, H1);

    k_agg<<<NNODE / 16, 256, 0, stream>>>(H1, rp, col, Agg);
    k_gemm128<<<(NNODE + 127) / 128, 256, 0, stream>>>(H1, Agg, Wb2s, Wb2n, b2, H2);

    k_gemmN16<<<(NNODE + 255) / 256, 256, 0, stream>>>(H2, Wb3n, G3);
    k_agg16<<<(NNODE + 127) / 128, 256, 0, stream>>>(G3, rp, col, AggG);
    k_gemm16s<<<(NNODE + 255) / 256, 256, 0, stream>>>(H2, Wb3s, AggG, b3, H3);

    k_score<<<(EPOS + ENEG + 255) / 256, 256, 0, stream>>>(H3, pos_u, pos_v,
                                                           neg_u, neg_v, out);
}

// Round 5
// 296.817 us; speedup vs baseline: 3.4125x; 1.0739x over previous
//
#include <hip/hip_runtime.h>

static constexpr int NNODE = 100000;
static constexpr int NEDGE = 1600000;
static constexpr int EPOS  = 100000;
static constexpr int ENEG  = 500000;
static constexpr int F     = 128;
static constexpr int CLS   = 16;
static constexpr int NBKT  = 392;      // buckets of 256 nodes (dst >> 8); 392*256 = 100352
static constexpr int BCAP  = 4608;     // bucket capacity (mean 4096, +8 sigma)
static constexpr int TILE  = 2048;     // edges per k_bin block
static constexpr int NTB   = (NEDGE + TILE - 1) / TILE;   // 782

using bf16x8 = __attribute__((ext_vector_type(8))) short;
using f32x4  = __attribute__((ext_vector_type(4))) float;

// ---------------- bf16 helpers ----------------

__device__ __forceinline__ ushort f2b(float f) {           // f32 -> bf16 RNE
    unsigned u = __float_as_uint(f);
    unsigned r = u + 0x7fffu + ((u >> 16) & 1u);
    return (ushort)(r >> 16);
}
__device__ __forceinline__ float b2f(ushort h) {
    return __uint_as_float(((unsigned)h) << 16);
}

__global__ void k_cast(const float* __restrict__ x, ushort* __restrict__ xb) {
    int i = blockIdx.x * 256 + threadIdx.x;   // one float4 per thread
    float4 v = ((const float4*)x)[i];
    ushort4 o; o.x = f2b(v.x); o.y = f2b(v.y); o.z = f2b(v.z); o.w = f2b(v.w);
    ((ushort4*)xb)[i] = o;
}

// weights f32 [K][C] -> bf16 grouped layout: dst[(k>>3)*C*8 + c*8 + (k&7)]
__global__ void k_wcast(const float* __restrict__ W1s, const float* __restrict__ W1n,
                        const float* __restrict__ W2s, const float* __restrict__ W2n,
                        const float* __restrict__ W3s, const float* __restrict__ W3n,
                        ushort* __restrict__ o1s, ushort* __restrict__ o1n,
                        ushort* __restrict__ o2s, ushort* __restrict__ o2n,
                        ushort* __restrict__ o3s, ushort* __restrict__ o3n) {
    const int b = blockIdx.x;
    const int t = threadIdx.x;
    const float* src; ushort* dst; int C; int idx;
    if      (b < 64)  { src = W1s; dst = o1s; C = 128; idx = b * 256 + t; }
    else if (b < 128) { src = W1n; dst = o1n; C = 128; idx = (b - 64) * 256 + t; }
    else if (b < 192) { src = W2s; dst = o2s; C = 128; idx = (b - 128) * 256 + t; }
    else if (b < 256) { src = W2n; dst = o2n; C = 128; idx = (b - 192) * 256 + t; }
    else if (b < 264) { src = W3s; dst = o3s; C = 16;  idx = (b - 256) * 256 + t; }
    else              { src = W3n; dst = o3n; C = 16;  idx = (b - 264) * 256 + t; }
    const int k = idx / C, c = idx % C;
    dst[(k >> 3) * C * 8 + c * 8 + (k & 7)] = f2b(src[idx]);
}

// ---------------- CSR build: bucket binning (phase 1) ----------------
// Packs edge as src | (dst&255)<<17, writes bucket-run-contiguous chunks.

__global__ __launch_bounds__(256) void k_bin(
    const int* __restrict__ src, const int* __restrict__ dst,
    uint* __restrict__ bins, int* __restrict__ gcount) {
    __shared__ int  hist[NBKT];
    __shared__ int  lofs[NBKT];
    __shared__ int  gbase[NBKT];
    __shared__ int  run[NBKT];
    __shared__ int  tmp[256];
    __shared__ uint stage[TILE];
    const int tid = threadIdx.x;
    const int e0  = blockIdx.x * TILE;

    for (int i = tid; i < NBKT; i += 256) hist[i] = 0;
    __syncthreads();
    #pragma unroll
    for (int j = 0; j < TILE / 256; ++j) {
        const int e = e0 + j * 256 + tid;
        if (e < NEDGE) atomicAdd(&hist[dst[e] >> 8], 1);
    }
    __syncthreads();
    // exclusive scan over NBKT (<=512) with 2 slots/thread
    const int i0 = 2 * tid, i1 = 2 * tid + 1;
    const int a0 = (i0 < NBKT) ? hist[i0] : 0;
    const int a1 = (i1 < NBKT) ? hist[i1] : 0;
    tmp[tid] = a0 + a1;
    __syncthreads();
    for (int off = 1; off < 256; off <<= 1) {
        int y = (tid >= off) ? tmp[tid - off] : 0;
        __syncthreads();
        tmp[tid] += y;
        __syncthreads();
    }
    const int pbase = tid ? tmp[tid - 1] : 0;
    if (i0 < NBKT) { lofs[i0] = pbase;      run[i0] = pbase; }
    if (i1 < NBKT) { lofs[i1] = pbase + a0; run[i1] = pbase + a0; }
    __syncthreads();
    for (int i = tid; i < NBKT; i += 256)
        gbase[i] = (hist[i] > 0) ? atomicAdd(&gcount[i], hist[i]) : 0;
    __syncthreads();
    #pragma unroll
    for (int j = 0; j < TILE / 256; ++j) {
        const int e = e0 + j * 256 + tid;
        if (e < NEDGE) {
            const int d = dst[e];
            const int b = d >> 8;
            const int r = atomicAdd(&run[b], 1);
            stage[r] = (uint)(src[e] | ((d & 255) << 17));
        }
    }
    __syncthreads();
    const int total = lofs[NBKT - 1] + hist[NBKT - 1];
    for (int i = tid; i < total; i += 256) {
        int lo = 0, hi = NBKT - 1;                  // largest b with lofs[b] <= i
        while (lo < hi) {
            const int mid = (lo + hi + 1) >> 1;
            if (lofs[mid] <= i) lo = mid; else hi = mid - 1;
        }
        bins[(size_t)lo * BCAP + gbase[lo] + (i - lofs[lo])] = stage[i];
    }
}

// exclusive scan of gcount[NBKT] -> ebase[NBKT]
__global__ void k_bscan(const int* __restrict__ gcount, int* __restrict__ ebase) {
    __shared__ int s[256];
    const int t = threadIdx.x;
    const int i0 = 2 * t, i1 = 2 * t + 1;
    const int a0 = (i0 < NBKT) ? gcount[i0] : 0;
    const int a1 = (i1 < NBKT) ? gcount[i1] : 0;
    s[t] = a0 + a1;
    __syncthreads();
    for (int off = 1; off < 256; off <<= 1) {
        int y = (t >= off) ? s[t - off] : 0;
        __syncthreads();
        s[t] += y;
        __syncthreads();
    }
    const int pbase = t ? s[t - 1] : 0;
    if (i0 < NBKT) ebase[i0] = pbase;
    if (i1 < NBKT) ebase[i1] = pbase + a0;
}

// ---------------- CSR build: per-bucket degree/scan/scatter (phase 2) ----------------

__global__ __launch_bounds__(256) void k_build(
    const uint* __restrict__ bins, const int* __restrict__ gcount,
    const int* __restrict__ ebase, int* __restrict__ rp, int* __restrict__ col) {
    __shared__ int ldeg[256];
    __shared__ int lrp[256];
    const int tid = threadIdx.x;
    const int b   = blockIdx.x;
    const int nbase = b * 256;
    const int cnt   = gcount[b];
    const int eb    = ebase[b];
    const uint* mybins = bins + (size_t)b * BCAP;

    ldeg[tid] = 0;
    __syncthreads();
    for (int i = tid; i < cnt; i += 256)
        atomicAdd(&ldeg[(mybins[i] >> 17) & 255], 1);
    __syncthreads();
    const int x = ldeg[tid];
    lrp[tid] = x;
    __syncthreads();
    for (int off = 1; off < 256; off <<= 1) {
        int y = (tid >= off) ? lrp[tid - off] : 0;
        __syncthreads();
        lrp[tid] += y;
        __syncthreads();
    }
    const int excl = lrp[tid] - x;
    rp[nbase + tid] = eb + excl;
    ldeg[tid] = excl;                 // running counters
    __syncthreads();
    for (int i = tid; i < cnt; i += 256) {
        const uint v = mybins[i];
        const int dlow = (v >> 17) & 255;
        const int p = atomicAdd(&ldeg[dlow], 1);
        col[eb + p] = (int)(v & 0x1FFFF);
    }
    if (b == NBKT - 1 && tid == 0) rp[NBKT * 256] = eb + cnt;   // sentinel
}

// ---------------- aggregation: mean of neighbor rows (bf16 -> bf16), width 128 ----------------

__global__ __launch_bounds__(256) void k_agg(
    const ushort* __restrict__ hin, const int* __restrict__ rp,
    const int* __restrict__ col, ushort* __restrict__ agg) {
    const int tid = threadIdx.x;
    const int row = blockIdx.x * 16 + (tid >> 4);   // 16 rows/block, 16 lanes/row
    const int l16 = tid & 15;
    const int p0 = rp[row];
    const int pe = rp[row + 1];
    const int d  = pe - p0;
    float s0[8] = {0, 0, 0, 0, 0, 0, 0, 0};
    float s1[8] = {0, 0, 0, 0, 0, 0, 0, 0};
    int p = p0;
    for (; p + 2 <= pe; p += 2) {
        const int u0 = col[p];
        const int u1 = col[p + 1];
        const bf16x8 a = *(const bf16x8*)(hin + (size_t)u0 * F + l16 * 8);
        const bf16x8 b = *(const bf16x8*)(hin + (size_t)u1 * F + l16 * 8);
        #pragma unroll
        for (int j = 0; j < 8; ++j) s0[j] += b2f((ushort)a[j]);
        #pragma unroll
        for (int j = 0; j < 8; ++j) s1[j] += b2f((ushort)b[j]);
    }
    if (p < pe) {
        const bf16x8 a = *(const bf16x8*)(hin + (size_t)col[p] * F + l16 * 8);
        #pragma unroll
        for (int j = 0; j < 8; ++j) s0[j] += b2f((ushort)a[j]);
    }
    const float inv = d > 0 ? 1.0f / (float)d : 0.0f;
    bf16x8 o;
    #pragma unroll
    for (int j = 0; j < 8; ++j) o[j] = (short)f2b((s0[j] + s1[j]) * inv);
    *(bf16x8*)(agg + (size_t)row * F + l16 * 8) = o;
}

// width-16 aggregation (for G3): 2 lanes/row, 128 rows/block
__global__ __launch_bounds__(256) void k_agg16(
    const ushort* __restrict__ G, const int* __restrict__ rp,
    const int* __restrict__ col, ushort* __restrict__ aggg) {
    const int tid  = threadIdx.x;
    const int row  = blockIdx.x * 128 + (tid >> 1);
    const int half = tid & 1;
    if (row >= NNODE) return;
    const int p0 = rp[row];
    const int pe = rp[row + 1];
    const int d  = pe - p0;
    float s0[8] = {0, 0, 0, 0, 0, 0, 0, 0};
    float s1[8] = {0, 0, 0, 0, 0, 0, 0, 0};
    int p = p0;
    for (; p + 2 <= pe; p += 2) {
        const int u0 = col[p];
        const int u1 = col[p + 1];
        const bf16x8 a = *(const bf16x8*)(G + (size_t)u0 * CLS + half * 8);
        const bf16x8 b = *(const bf16x8*)(G + (size_t)u1 * CLS + half * 8);
        #pragma unroll
        for (int j = 0; j < 8; ++j) s0[j] += b2f((ushort)a[j]);
        #pragma unroll
        for (int j = 0; j < 8; ++j) s1[j] += b2f((ushort)b[j]);
    }
    if (p < pe) {
        const bf16x8 a = *(const bf16x8*)(G + (size_t)col[p] * CLS + half * 8);
        #pragma unroll
        for (int j = 0; j < 8; ++j) s0[j] += b2f((ushort)a[j]);
    }
    const float inv = d > 0 ? 1.0f / (float)d : 0.0f;
    bf16x8 o;
    #pragma unroll
    for (int j = 0; j < 8; ++j) o[j] = (short)f2b((s0[j] + s1[j]) * inv);
    *(bf16x8*)(aggg + (size_t)row * CLS + half * 8) = o;
}

// ---------------- MFMA GEMM: out = relu(A1@Ws + A2@Wn + b), N=128 ----------------

__global__ __launch_bounds__(256) void k_gemm128(
    const ushort* __restrict__ A1, const ushort* __restrict__ A2,
    const ushort* __restrict__ Ws2, const ushort* __restrict__ Wn2,
    const float* __restrict__ bias, ushort* __restrict__ outb) {
    __shared__ ushort Wl[16384];                 // 32 KB: one weight matrix
    const int tid  = threadIdx.x;
    const int wv   = tid >> 6;
    const int lane = tid & 63;
    const int l16  = lane & 15;
    const int lk   = lane >> 4;
    const int rbase = blockIdx.x * 128 + wv * 32;

    f32x4 acc0[8], acc1[8];
    #pragma unroll
    for (int n = 0; n < 8; ++n) { acc0[n] = (f32x4){0,0,0,0}; acc1[n] = (f32x4){0,0,0,0}; }

    const int r0 = rbase + l16       < NNODE ? rbase + l16       : NNODE - 1;
    const int r1 = rbase + 16 + l16  < NNODE ? rbase + 16 + l16  : NNODE - 1;
    const size_t ra0 = (size_t)r0 * F + lk * 8;
    const size_t ra1 = (size_t)r1 * F + lk * 8;

    #pragma unroll
    for (int mat = 0; mat < 2; ++mat) {
        const ushort* W2 = mat ? Wn2 : Ws2;
        const ushort* A  = mat ? A2  : A1;
        __syncthreads();
        #pragma unroll
        for (int i = 0; i < 8; ++i)
            *(bf16x8*)&Wl[tid * 8 + i * 2048] = *(const bf16x8*)&W2[tid * 8 + i * 2048];
        __syncthreads();
        #pragma unroll
        for (int kb = 0; kb < 4; ++kb) {
            const bf16x8 a0 = *(const bf16x8*)(A + ra0 + kb * 32);
            const bf16x8 a1 = *(const bf16x8*)(A + ra1 + kb * 32);
            const int kg = kb * 4 + lk;
            #pragma unroll
            for (int n = 0; n < 8; ++n) {
                const bf16x8 b = *(const bf16x8*)&Wl[kg * 1024 + (n * 16 + l16) * 8];
                acc0[n] = __builtin_amdgcn_mfma_f32_16x16x32_bf16(a0, b, acc0[n], 0, 0, 0);
                acc1[n] = __builtin_amdgcn_mfma_f32_16x16x32_bf16(a1, b, acc1[n], 0, 0, 0);
            }
        }
    }

    #pragma unroll
    for (int n = 0; n < 8; ++n) {
        const int c = n * 16 + l16;
        const float bv = bias[c];
        #pragma unroll
        for (int j = 0; j < 4; ++j) {
            const int rr0 = rbase + lk * 4 + j;
            const int rr1 = rbase + 16 + lk * 4 + j;
            if (rr0 < NNODE) outb[(size_t)rr0 * F + c] = f2b(fmaxf(acc0[n][j] + bv, 0.f));
            if (rr1 < NNODE) outb[(size_t)rr1 * F + c] = f2b(fmaxf(acc1[n][j] + bv, 0.f));
        }
    }
}

// ---------------- MFMA GEMM: G = A@W2 (bf16 out, no bias), N=16 ----------------

__global__ __launch_bounds__(256) void k_gemmN16(
    const ushort* __restrict__ A, const ushort* __restrict__ W2,
    ushort* __restrict__ G) {
    __shared__ ushort Wl[2048];
    const int tid  = threadIdx.x;
    const int wv   = tid >> 6;
    const int lane = tid & 63;
    const int l16  = lane & 15;
    const int lk   = lane >> 4;
    const int rbase = blockIdx.x * 256 + wv * 64;

    *(bf16x8*)&Wl[tid * 8] = *(const bf16x8*)&W2[tid * 8];
    __syncthreads();

    f32x4 acc[4];
    #pragma unroll
    for (int rt = 0; rt < 4; ++rt) acc[rt] = (f32x4){0,0,0,0};

    #pragma unroll
    for (int kb = 0; kb < 4; ++kb) {
        const int kg = kb * 4 + lk;
        const bf16x8 b = *(const bf16x8*)&Wl[kg * 128 + l16 * 8];
        #pragma unroll
        for (int rt = 0; rt < 4; ++rt) {
            int row = rbase + rt * 16 + l16;
            if (row >= NNODE) row = NNODE - 1;
            const bf16x8 a = *(const bf16x8*)(A + (size_t)row * F + kb * 32 + lk * 8);
            acc[rt] = __builtin_amdgcn_mfma_f32_16x16x32_bf16(a, b, acc[rt], 0, 0, 0);
        }
    }

    #pragma unroll
    for (int rt = 0; rt < 4; ++rt) {
        #pragma unroll
        for (int j = 0; j < 4; ++j) {
            const int rr = rbase + rt * 16 + lk * 4 + j;
            if (rr < NNODE) G[(size_t)rr * CLS + l16] = f2b(acc[rt][j]);
        }
    }
}

// ---------------- final: H3 = A@Ws + AggG + b (f32 out), N=16 ----------------

__global__ __launch_bounds__(256) void k_gemm16s(
    const ushort* __restrict__ A, const ushort* __restrict__ Ws2,
    const ushort* __restrict__ aggg, const float* __restrict__ bias,
    float* __restrict__ out) {
    __shared__ ushort Wl[2048];
    const int tid  = threadIdx.x;
    const int wv   = tid >> 6;
    const int lane = tid & 63;
    const int l16  = lane & 15;
    const int lk   = lane >> 4;
    const int rbase = blockIdx.x * 256 + wv * 64;

    *(bf16x8*)&Wl[tid * 8] = *(const bf16x8*)&Ws2[tid * 8];
    __syncthreads();

    f32x4 acc[4];
    #pragma unroll
    for (int rt = 0; rt < 4; ++rt) acc[rt] = (f32x4){0,0,0,0};

    #pragma unroll
    for (int kb = 0; kb < 4; ++kb) {
        const int kg = kb * 4 + lk;
        const bf16x8 b = *(const bf16x8*)&Wl[kg * 128 + l16 * 8];
        #pragma unroll
        for (int rt = 0; rt < 4; ++rt) {
            int row = rbase + rt * 16 + l16;
            if (row >= NNODE) row = NNODE - 1;
            const bf16x8 a = *(const bf16x8*)(A + (size_t)row * F + kb * 32 + lk * 8);
            acc[rt] = __builtin_amdgcn_mfma_f32_16x16x32_bf16(a, b, acc[rt], 0, 0, 0);
        }
    }

    const float bv = bias[l16];
    #pragma unroll
    for (int rt = 0; rt < 4; ++rt) {
        #pragma unroll
        for (int j = 0; j < 4; ++j) {
            const int rr = rbase + rt * 16 + lk * 4 + j;
            if (rr < NNODE)
                out[(size_t)rr * CLS + l16] =
                    acc[rt][j] + b2f(aggg[(size_t)rr * CLS + l16]) + bv;
        }
    }
}

// ---------------- edge scoring ----------------

__global__ void k_score(const float* __restrict__ H3,
                        const int* __restrict__ pu, const int* __restrict__ pv,
                        const int* __restrict__ nu, const int* __restrict__ nv,
                        float* __restrict__ out) {
    int i = blockIdx.x * 256 + threadIdx.x;
    if (i >= EPOS + ENEG) return;
    int u, v, o;
    if (i < EPOS) { u = pu[i]; v = pv[i]; o = i; }
    else { int j = i - EPOS; u = nu[j]; v = nv[j]; o = EPOS + j; }
    const float4* a = (const float4*)(H3 + (size_t)u * CLS);
    const float4* b = (const float4*)(H3 + (size_t)v * CLS);
    float s = 0.f;
    #pragma unroll
    for (int r = 0; r < 4; ++r) {
        const float4 av = a[r], bv = b[r];
        s += av.x * bv.x + av.y * bv.y + av.z * bv.z + av.w * bv.w;
    }
    out[o] = s;
}

// ---------------- launch ----------------

extern "C" void kernel_launch(void* const* d_in, const int* in_sizes, int n_in,
                              void* d_out, int out_size, void* d_ws, size_t ws_size,
                              hipStream_t stream) {
    const float* x     = (const float*)d_in[0];
    const int*   src   = (const int*)d_in[1];
    const int*   dst   = (const int*)d_in[2];
    const int*   pos_u = (const int*)d_in[3];
    const int*   pos_v = (const int*)d_in[4];
    const int*   neg_u = (const int*)d_in[5];
    const int*   neg_v = (const int*)d_in[6];
    const float* W1s = (const float*)d_in[7];
    const float* W1n = (const float*)d_in[8];
    const float* b1  = (const float*)d_in[9];
    const float* W2s = (const float*)d_in[10];
    const float* W2n = (const float*)d_in[11];
    const float* b2  = (const float*)d_in[12];
    const float* W3s = (const float*)d_in[13];
    const float* W3n = (const float*)d_in[14];
    const float* b3  = (const float*)d_in[15];
    float* out = (float*)d_out;

    char* ws = (char*)d_ws;
    size_t off = 0;
    int* rp     = (int*)(ws + off); off += (size_t)(NBKT * 256 + 256) * 4;
    int* gcount = (int*)(ws + off); off += 512 * 4;
    int* ebase  = (int*)(ws + off); off += 512 * 4;
    off = (off + 255) & ~(size_t)255;
    uint* bins  = (uint*)(ws + off); off += (size_t)NBKT * BCAP * 4;
    int*  col   = (int*)(ws + off);  off += (size_t)NEDGE * 4;
    off = (off + 255) & ~(size_t)255;
    ushort* Xb   = (ushort*)(ws + off); off += (size_t)NNODE * F * 2;
    off = (off + 255) & ~(size_t)255;
    ushort* H1   = (ushort*)(ws + off); off += (size_t)NNODE * F * 2;
    off = (off + 255) & ~(size_t)255;
    ushort* H2   = (ushort*)(ws + off); off += (size_t)NNODE * F * 2;
    off = (off + 255) & ~(size_t)255;
    ushort* Agg  = (ushort*)(ws + off); off += (size_t)NNODE * F * 2;
    off = (off + 255) & ~(size_t)255;
    ushort* G3   = (ushort*)(ws + off); off += (size_t)NNODE * CLS * 2;
    off = (off + 255) & ~(size_t)255;
    ushort* AggG = (ushort*)(ws + off); off += (size_t)NNODE * CLS * 2;
    off = (off + 255) & ~(size_t)255;
    float*  H3   = (float*)(ws + off);  off += (size_t)NNODE * CLS * 4;
    off = (off + 255) & ~(size_t)255;
    ushort* Wb1s = (ushort*)(ws + off); off += 16384 * 2;
    ushort* Wb1n = (ushort*)(ws + off); off += 16384 * 2;
    ushort* Wb2s = (ushort*)(ws + off); off += 16384 * 2;
    ushort* Wb2n = (ushort*)(ws + off); off += 16384 * 2;
    ushort* Wb3s = (ushort*)(ws + off); off += 2048 * 2;
    ushort* Wb3n = (ushort*)(ws + off); off += 2048 * 2;

    hipMemsetAsync(gcount, 0, 512 * 4, stream);

    k_cast<<<NNODE * F / 4 / 256, 256, 0, stream>>>(x, Xb);
    k_wcast<<<272, 256, 0, stream>>>(W1s, W1n, W2s, W2n, W3s, W3n,
                                     Wb1s, Wb1n, Wb2s, Wb2n, Wb3s, Wb3n);

    k_bin<<<NTB, 256, 0, stream>>>(src, dst, bins, gcount);
    k_bscan<<<1, 256, 0, stream>>>(gcount, ebase);
    k_build<<<NBKT, 256, 0, stream>>>(bins, gcount, ebase, rp, col);

    k_agg<<<NNODE / 16, 256, 0, stream>>>(Xb, rp, col, Agg);
    k_gemm128<<<(NNODE + 127) / 128, 256, 0, stream>>>(Xb, Agg, Wb1s, Wb1n, b1, H1);

    k_agg<<<NNODE / 16, 256, 0, stream>>>(H1, rp, col, Agg);
    k_gemm128<<<(NNODE + 127) / 128, 256, 0, stream>>>(H1, Agg, Wb2s, Wb2n, b2, H2);

    k_gemmN16<<<(NNODE + 255) / 256, 256, 0, stream>>>(H2, Wb3n, G3);
    k_agg16<<<(NNODE + 127) / 128, 256, 0, stream>>>(G3, rp, col, AggG);
    k_gemm16s<<<(NNODE + 255) / 256, 256, 0, stream>>>(H2, Wb3s, AggG, b3, H3);

    k_score<<<(EPOS + ENEG + 255) / 256, 256, 0, stream>>>(H3, pos_u, pos_v,
                                                           neg_u, neg_v, out);
}

// Round 6
// 292.479 us; speedup vs baseline: 3.4631x; 1.0148x over previous
//
#include <hip/hip_runtime.h>

static constexpr int NNODE = 100000;
static constexpr int NEDGE = 1600000;
static constexpr int EPOS  = 100000;
static constexpr int ENEG  = 500000;
static constexpr int F     = 128;
static constexpr int CLS   = 16;
static constexpr int NBKT  = 392;      // buckets of 256 nodes (dst >> 8); 392*256 = 100352
static constexpr int BCAP  = 4608;     // bucket capacity (mean 4096, +8 sigma)
static constexpr int TILE  = 2048;     // edges per k_bin block
static constexpr int NTB   = (NEDGE + TILE - 1) / TILE;   // 782

using bf16x8 = __attribute__((ext_vector_type(8))) short;
using f32x4  = __attribute__((ext_vector_type(4))) float;

// ---------------- bf16 helpers ----------------

__device__ __forceinline__ ushort f2b(float f) {           // f32 -> bf16 RNE
    unsigned u = __float_as_uint(f);
    unsigned r = u + 0x7fffu + ((u >> 16) & 1u);
    return (ushort)(r >> 16);
}
__device__ __forceinline__ float b2f(ushort h) {
    return __uint_as_float(((unsigned)h) << 16);
}

__global__ void k_cast(const float* __restrict__ x, ushort* __restrict__ xb) {
    int i = blockIdx.x * 256 + threadIdx.x;   // one float4 per thread
    float4 v = ((const float4*)x)[i];
    ushort4 o; o.x = f2b(v.x); o.y = f2b(v.y); o.z = f2b(v.z); o.w = f2b(v.w);
    ((ushort4*)xb)[i] = o;
}

// weights f32 [K][C] -> bf16 grouped layout: dst[(k>>3)*C*8 + c*8 + (k&7)]
__global__ void k_wcast(const float* __restrict__ W1s, const float* __restrict__ W1n,
                        const float* __restrict__ W2s, const float* __restrict__ W2n,
                        const float* __restrict__ W3s, const float* __restrict__ W3n,
                        ushort* __restrict__ o1s, ushort* __restrict__ o1n,
                        ushort* __restrict__ o2s, ushort* __restrict__ o2n,
                        ushort* __restrict__ o3s, ushort* __restrict__ o3n) {
    const int b = blockIdx.x;
    const int t = threadIdx.x;
    const float* src; ushort* dst; int C; int idx;
    if      (b < 64)  { src = W1s; dst = o1s; C = 128; idx = b * 256 + t; }
    else if (b < 128) { src = W1n; dst = o1n; C = 128; idx = (b - 64) * 256 + t; }
    else if (b < 192) { src = W2s; dst = o2s; C = 128; idx = (b - 128) * 256 + t; }
    else if (b < 256) { src = W2n; dst = o2n; C = 128; idx = (b - 192) * 256 + t; }
    else if (b < 264) { src = W3s; dst = o3s; C = 16;  idx = (b - 256) * 256 + t; }
    else              { src = W3n; dst = o3n; C = 16;  idx = (b - 264) * 256 + t; }
    const int k = idx / C, c = idx % C;
    dst[(k >> 3) * C * 8 + c * 8 + (k & 7)] = f2b(src[idx]);
}

// ---------------- CSR build: bucket binning (phase 1) ----------------
// Packs edge as src | (dst&255)<<17, writes bucket-run-contiguous chunks.

__global__ __launch_bounds__(256) void k_bin(
    const int* __restrict__ src, const int* __restrict__ dst,
    uint* __restrict__ bins, int* __restrict__ gcount) {
    __shared__ int  hist[NBKT];
    __shared__ int  lofs[NBKT];
    __shared__ int  gbase[NBKT];
    __shared__ int  run[NBKT];
    __shared__ int  tmp[256];
    __shared__ uint stage[TILE];
    const int tid = threadIdx.x;
    const int e0  = blockIdx.x * TILE;

    for (int i = tid; i < NBKT; i += 256) hist[i] = 0;
    __syncthreads();
    #pragma unroll
    for (int j = 0; j < TILE / 256; ++j) {
        const int e = e0 + j * 256 + tid;
        if (e < NEDGE) atomicAdd(&hist[dst[e] >> 8], 1);
    }
    __syncthreads();
    // exclusive scan over NBKT (<=512) with 2 slots/thread
    const int i0 = 2 * tid, i1 = 2 * tid + 1;
    const int a0 = (i0 < NBKT) ? hist[i0] : 0;
    const int a1 = (i1 < NBKT) ? hist[i1] : 0;
    tmp[tid] = a0 + a1;
    __syncthreads();
    for (int off = 1; off < 256; off <<= 1) {
        int y = (tid >= off) ? tmp[tid - off] : 0;
        __syncthreads();
        tmp[tid] += y;
        __syncthreads();
    }
    const int pbase = tid ? tmp[tid - 1] : 0;
    if (i0 < NBKT) { lofs[i0] = pbase;      run[i0] = pbase; }
    if (i1 < NBKT) { lofs[i1] = pbase + a0; run[i1] = pbase + a0; }
    __syncthreads();
    for (int i = tid; i < NBKT; i += 256)
        gbase[i] = (hist[i] > 0) ? atomicAdd(&gcount[i], hist[i]) : 0;
    __syncthreads();
    #pragma unroll
    for (int j = 0; j < TILE / 256; ++j) {
        const int e = e0 + j * 256 + tid;
        if (e < NEDGE) {
            const int d = dst[e];
            const int b = d >> 8;
            const int r = atomicAdd(&run[b], 1);
            stage[r] = (uint)(src[e] | ((d & 255) << 17));
        }
    }
    __syncthreads();
    const int total = lofs[NBKT - 1] + hist[NBKT - 1];
    for (int i = tid; i < total; i += 256) {
        int lo = 0, hi = NBKT - 1;                  // largest b with lofs[b] <= i
        while (lo < hi) {
            const int mid = (lo + hi + 1) >> 1;
            if (lofs[mid] <= i) lo = mid; else hi = mid - 1;
        }
        bins[(size_t)lo * BCAP + gbase[lo] + (i - lofs[lo])] = stage[i];
    }
}

// exclusive scan of gcount[NBKT] -> ebase[NBKT]
__global__ void k_bscan(const int* __restrict__ gcount, int* __restrict__ ebase) {
    __shared__ int s[256];
    const int t = threadIdx.x;
    const int i0 = 2 * t, i1 = 2 * t + 1;
    const int a0 = (i0 < NBKT) ? gcount[i0] : 0;
    const int a1 = (i1 < NBKT) ? gcount[i1] : 0;
    s[t] = a0 + a1;
    __syncthreads();
    for (int off = 1; off < 256; off <<= 1) {
        int y = (t >= off) ? s[t - off] : 0;
        __syncthreads();
        s[t] += y;
        __syncthreads();
    }
    const int pbase = t ? s[t - 1] : 0;
    if (i0 < NBKT) ebase[i0] = pbase;
    if (i1 < NBKT) ebase[i1] = pbase + a0;
}

// ---------------- CSR build: per-bucket degree/scan/scatter (phase 2) ----------------

__global__ __launch_bounds__(256) void k_build(
    const uint* __restrict__ bins, const int* __restrict__ gcount,
    const int* __restrict__ ebase, int* __restrict__ rp, int* __restrict__ col) {
    __shared__ int ldeg[256];
    __shared__ int lrp[256];
    const int tid = threadIdx.x;
    const int b   = blockIdx.x;
    const int nbase = b * 256;
    const int cnt   = gcount[b];
    const int eb    = ebase[b];
    const uint* mybins = bins + (size_t)b * BCAP;

    ldeg[tid] = 0;
    __syncthreads();
    for (int i = tid; i < cnt; i += 256)
        atomicAdd(&ldeg[(mybins[i] >> 17) & 255], 1);
    __syncthreads();
    const int x = ldeg[tid];
    lrp[tid] = x;
    __syncthreads();
    for (int off = 1; off < 256; off <<= 1) {
        int y = (tid >= off) ? lrp[tid - off] : 0;
        __syncthreads();
        lrp[tid] += y;
        __syncthreads();
    }
    const int excl = lrp[tid] - x;
    rp[nbase + tid] = eb + excl;
    ldeg[tid] = excl;                 // running counters
    __syncthreads();
    for (int i = tid; i < cnt; i += 256) {
        const uint v = mybins[i];
        const int dlow = (v >> 17) & 255;
        const int p = atomicAdd(&ldeg[dlow], 1);
        col[eb + p] = (int)(v & 0x1FFFF);
    }
    if (b == NBKT - 1 && tid == 0) rp[NBKT * 256] = eb + cnt;   // sentinel
}

// ---------------- aggregation: mean of neighbor rows (bf16 -> bf16), width 128 ----------------
// 4-way unrolled: 4 col loads + 4 row gathers in flight per lane.

__global__ __launch_bounds__(256) void k_agg(
    const ushort* __restrict__ hin, const int* __restrict__ rp,
    const int* __restrict__ col, ushort* __restrict__ agg) {
    const int tid = threadIdx.x;
    const int row = blockIdx.x * 16 + (tid >> 4);   // 16 rows/block, 16 lanes/row
    const int l16 = tid & 15;
    const int p0 = rp[row];
    const int pe = rp[row + 1];
    const int d  = pe - p0;
    float s0[8] = {0, 0, 0, 0, 0, 0, 0, 0};
    float s1[8] = {0, 0, 0, 0, 0, 0, 0, 0};
    float s2[8] = {0, 0, 0, 0, 0, 0, 0, 0};
    float s3[8] = {0, 0, 0, 0, 0, 0, 0, 0};
    int p = p0;
    for (; p + 4 <= pe; p += 4) {
        const int u0 = col[p];
        const int u1 = col[p + 1];
        const int u2 = col[p + 2];
        const int u3 = col[p + 3];
        const bf16x8 a = *(const bf16x8*)(hin + (size_t)u0 * F + l16 * 8);
        const bf16x8 b = *(const bf16x8*)(hin + (size_t)u1 * F + l16 * 8);
        const bf16x8 c = *(const bf16x8*)(hin + (size_t)u2 * F + l16 * 8);
        const bf16x8 e = *(const bf16x8*)(hin + (size_t)u3 * F + l16 * 8);
        #pragma unroll
        for (int j = 0; j < 8; ++j) s0[j] += b2f((ushort)a[j]);
        #pragma unroll
        for (int j = 0; j < 8; ++j) s1[j] += b2f((ushort)b[j]);
        #pragma unroll
        for (int j = 0; j < 8; ++j) s2[j] += b2f((ushort)c[j]);
        #pragma unroll
        for (int j = 0; j < 8; ++j) s3[j] += b2f((ushort)e[j]);
    }
    for (; p < pe; ++p) {
        const bf16x8 a = *(const bf16x8*)(hin + (size_t)col[p] * F + l16 * 8);
        #pragma unroll
        for (int j = 0; j < 8; ++j) s0[j] += b2f((ushort)a[j]);
    }
    const float inv = d > 0 ? 1.0f / (float)d : 0.0f;
    bf16x8 o;
    #pragma unroll
    for (int j = 0; j < 8; ++j)
        o[j] = (short)f2b(((s0[j] + s1[j]) + (s2[j] + s3[j])) * inv);
    *(bf16x8*)(agg + (size_t)row * F + l16 * 8) = o;
}

// width-16 aggregation (for G3): 2 lanes/row, 128 rows/block, 4-way unrolled
__global__ __launch_bounds__(256) void k_agg16(
    const ushort* __restrict__ G, const int* __restrict__ rp,
    const int* __restrict__ col, ushort* __restrict__ aggg) {
    const int tid  = threadIdx.x;
    const int row  = blockIdx.x * 128 + (tid >> 1);
    const int half = tid & 1;
    if (row >= NNODE) return;
    const int p0 = rp[row];
    const int pe = rp[row + 1];
    const int d  = pe - p0;
    float s0[8] = {0, 0, 0, 0, 0, 0, 0, 0};
    float s1[8] = {0, 0, 0, 0, 0, 0, 0, 0};
    float s2[8] = {0, 0, 0, 0, 0, 0, 0, 0};
    float s3[8] = {0, 0, 0, 0, 0, 0, 0, 0};
    int p = p0;
    for (; p + 4 <= pe; p += 4) {
        const int u0 = col[p];
        const int u1 = col[p + 1];
        const int u2 = col[p + 2];
        const int u3 = col[p + 3];
        const bf16x8 a = *(const bf16x8*)(G + (size_t)u0 * CLS + half * 8);
        const bf16x8 b = *(const bf16x8*)(G + (size_t)u1 * CLS + half * 8);
        const bf16x8 c = *(const bf16x8*)(G + (size_t)u2 * CLS + half * 8);
        const bf16x8 e = *(const bf16x8*)(G + (size_t)u3 * CLS + half * 8);
        #pragma unroll
        for (int j = 0; j < 8; ++j) s0[j] += b2f((ushort)a[j]);
        #pragma unroll
        for (int j = 0; j < 8; ++j) s1[j] += b2f((ushort)b[j]);
        #pragma unroll
        for (int j = 0; j < 8; ++j) s2[j] += b2f((ushort)c[j]);
        #pragma unroll
        for (int j = 0; j < 8; ++j) s3[j] += b2f((ushort)e[j]);
    }
    for (; p < pe; ++p) {
        const bf16x8 a = *(const bf16x8*)(G + (size_t)col[p] * CLS + half * 8);
        #pragma unroll
        for (int j = 0; j < 8; ++j) s0[j] += b2f((ushort)a[j]);
    }
    const float inv = d > 0 ? 1.0f / (float)d : 0.0f;
    bf16x8 o;
    #pragma unroll
    for (int j = 0; j < 8; ++j)
        o[j] = (short)f2b(((s0[j] + s1[j]) + (s2[j] + s3[j])) * inv);
    *(bf16x8*)(aggg + (size_t)row * CLS + half * 8) = o;
}

// ---------------- MFMA GEMM: out = relu(A1@Ws + A2@Wn + b), N=128 ----------------

__global__ __launch_bounds__(256) void k_gemm128(
    const ushort* __restrict__ A1, const ushort* __restrict__ A2,
    const ushort* __restrict__ Ws2, const ushort* __restrict__ Wn2,
    const float* __restrict__ bias, ushort* __restrict__ outb) {
    __shared__ ushort Wl[16384];                 // 32 KB: one weight matrix
    const int tid  = threadIdx.x;
    const int wv   = tid >> 6;
    const int lane = tid & 63;
    const int l16  = lane & 15;
    const int lk   = lane >> 4;
    const int rbase = blockIdx.x * 128 + wv * 32;

    f32x4 acc0[8], acc1[8];
    #pragma unroll
    for (int n = 0; n < 8; ++n) { acc0[n] = (f32x4){0,0,0,0}; acc1[n] = (f32x4){0,0,0,0}; }

    const int r0 = rbase + l16       < NNODE ? rbase + l16       : NNODE - 1;
    const int r1 = rbase + 16 + l16  < NNODE ? rbase + 16 + l16  : NNODE - 1;
    const size_t ra0 = (size_t)r0 * F + lk * 8;
    const size_t ra1 = (size_t)r1 * F + lk * 8;

    #pragma unroll
    for (int mat = 0; mat < 2; ++mat) {
        const ushort* W2 = mat ? Wn2 : Ws2;
        const ushort* A  = mat ? A2  : A1;
        __syncthreads();
        #pragma unroll
        for (int i = 0; i < 8; ++i)
            *(bf16x8*)&Wl[tid * 8 + i * 2048] = *(const bf16x8*)&W2[tid * 8 + i * 2048];
        __syncthreads();
        #pragma unroll
        for (int kb = 0; kb < 4; ++kb) {
            const bf16x8 a0 = *(const bf16x8*)(A + ra0 + kb * 32);
            const bf16x8 a1 = *(const bf16x8*)(A + ra1 + kb * 32);
            const int kg = kb * 4 + lk;
            #pragma unroll
            for (int n = 0; n < 8; ++n) {
                const bf16x8 b = *(const bf16x8*)&Wl[kg * 1024 + (n * 16 + l16) * 8];
                acc0[n] = __builtin_amdgcn_mfma_f32_16x16x32_bf16(a0, b, acc0[n], 0, 0, 0);
                acc1[n] = __builtin_amdgcn_mfma_f32_16x16x32_bf16(a1, b, acc1[n], 0, 0, 0);
            }
        }
    }

    #pragma unroll
    for (int n = 0; n < 8; ++n) {
        const int c = n * 16 + l16;
        const float bv = bias[c];
        #pragma unroll
        for (int j = 0; j < 4; ++j) {
            const int rr0 = rbase + lk * 4 + j;
            const int rr1 = rbase + 16 + lk * 4 + j;
            if (rr0 < NNODE) outb[(size_t)rr0 * F + c] = f2b(fmaxf(acc0[n][j] + bv, 0.f));
            if (rr1 < NNODE) outb[(size_t)rr1 * F + c] = f2b(fmaxf(acc1[n][j] + bv, 0.f));
        }
    }
}

// ---------------- MFMA GEMM: G = A@W2 (bf16 out, no bias), N=16 ----------------

__global__ __launch_bounds__(256) void k_gemmN16(
    const ushort* __restrict__ A, const ushort* __restrict__ W2,
    ushort* __restrict__ G) {
    __shared__ ushort Wl[2048];
    const int tid  = threadIdx.x;
    const int wv   = tid >> 6;
    const int lane = tid & 63;
    const int l16  = lane & 15;
    const int lk   = lane >> 4;
    const int rbase = blockIdx.x * 256 + wv * 64;

    *(bf16x8*)&Wl[tid * 8] = *(const bf16x8*)&W2[tid * 8];
    __syncthreads();

    f32x4 acc[4];
    #pragma unroll
    for (int rt = 0; rt < 4; ++rt) acc[rt] = (f32x4){0,0,0,0};

    #pragma unroll
    for (int kb = 0; kb < 4; ++kb) {
        const int kg = kb * 4 + lk;
        const bf16x8 b = *(const bf16x8*)&Wl[kg * 128 + l16 * 8];
        #pragma unroll
        for (int rt = 0; rt < 4; ++rt) {
            int row = rbase + rt * 16 + l16;
            if (row >= NNODE) row = NNODE - 1;
            const bf16x8 a = *(const bf16x8*)(A + (size_t)row * F + kb * 32 + lk * 8);
            acc[rt] = __builtin_amdgcn_mfma_f32_16x16x32_bf16(a, b, acc[rt], 0, 0, 0);
        }
    }

    #pragma unroll
    for (int rt = 0; rt < 4; ++rt) {
        #pragma unroll
        for (int j = 0; j < 4; ++j) {
            const int rr = rbase + rt * 16 + lk * 4 + j;
            if (rr < NNODE) G[(size_t)rr * CLS + l16] = f2b(acc[rt][j]);
        }
    }
}

// ---------------- final: H3 = A@Ws + AggG + b (f32 out), N=16 ----------------

__global__ __launch_bounds__(256) void k_gemm16s(
    const ushort* __restrict__ A, const ushort* __restrict__ Ws2,
    const ushort* __restrict__ aggg, const float* __restrict__ bias,
    float* __restrict__ out) {
    __shared__ ushort Wl[2048];
    const int tid  = threadIdx.x;
    const int wv   = tid >> 6;
    const int lane = tid & 63;
    const int l16  = lane & 15;
    const int lk   = lane >> 4;
    const int rbase = blockIdx.x * 256 + wv * 64;

    *(bf16x8*)&Wl[tid * 8] = *(const bf16x8*)&Ws2[tid * 8];
    __syncthreads();

    f32x4 acc[4];
    #pragma unroll
    for (int rt = 0; rt < 4; ++rt) acc[rt] = (f32x4){0,0,0,0};

    #pragma unroll
    for (int kb = 0; kb < 4; ++kb) {
        const int kg = kb * 4 + lk;
        const bf16x8 b = *(const bf16x8*)&Wl[kg * 128 + l16 * 8];
        #pragma unroll
        for (int rt = 0; rt < 4; ++rt) {
            int row = rbase + rt * 16 + l16;
            if (row >= NNODE) row = NNODE - 1;
            const bf16x8 a = *(const bf16x8*)(A + (size_t)row * F + kb * 32 + lk * 8);
            acc[rt] = __builtin_amdgcn_mfma_f32_16x16x32_bf16(a, b, acc[rt], 0, 0, 0);
        }
    }

    const float bv = bias[l16];
    #pragma unroll
    for (int rt = 0; rt < 4; ++rt) {
        #pragma unroll
        for (int j = 0; j < 4; ++j) {
            const int rr = rbase + rt * 16 + lk * 4 + j;
            if (rr < NNODE)
                out[(size_t)rr * CLS + l16] =
                    acc[rt][j] + b2f(aggg[(size_t)rr * CLS + l16]) + bv;
        }
    }
}

// ---------------- edge scoring ----------------

__global__ void k_score(const float* __restrict__ H3,
                        const int* __restrict__ pu, const int* __restrict__ pv,
                        const int* __restrict__ nu, const int* __restrict__ nv,
                        float* __restrict__ out) {
    int i = blockIdx.x * 256 + threadIdx.x;
    if (i >= EPOS + ENEG) return;
    int u, v, o;
    if (i < EPOS) { u = pu[i]; v = pv[i]; o = i; }
    else { int j = i - EPOS; u = nu[j]; v = nv[j]; o = EPOS + j; }
    const float4* a = (const float4*)(H3 + (size_t)u * CLS);
    const float4* b = (const float4*)(H3 + (size_t)v * CLS);
    float s = 0.f;
    #pragma unroll
    for (int r = 0; r < 4; ++r) {
        const float4 av = a[r], bv = b[r];
        s += av.x * bv.x + av.y * bv.y + av.z * bv.z + av.w * bv.w;
    }
    out[o] = s;
}

// ---------------- launch ----------------

extern "C" void kernel_launch(void* const* d_in, const int* in_sizes, int n_in,
                              void* d_out, int out_size, void* d_ws, size_t ws_size,
                              hipStream_t stream) {
    const float* x     = (const float*)d_in[0];
    const int*   src   = (const int*)d_in[1];
    const int*   dst   = (const int*)d_in[2];
    const int*   pos_u = (const int*)d_in[3];
    const int*   pos_v = (const int*)d_in[4];
    const int*   neg_u = (const int*)d_in[5];
    const int*   neg_v = (const int*)d_in[6];
    const float* W1s = (const float*)d_in[7];
    const float* W1n = (const float*)d_in[8];
    const float* b1  = (const float*)d_in[9];
    const float* W2s = (const float*)d_in[10];
    const float* W2n = (const float*)d_in[11];
    const float* b2  = (const float*)d_in[12];
    const float* W3s = (const float*)d_in[13];
    const float* W3n = (const float*)d_in[14];
    const float* b3  = (const float*)d_in[15];
    float* out = (float*)d_out;

    char* ws = (char*)d_ws;
    size_t off = 0;
    int* rp     = (int*)(ws + off); off += (size_t)(NBKT * 256 + 256) * 4;
    int* gcount = (int*)(ws + off); off += 512 * 4;
    int* ebase  = (int*)(ws + off); off += 512 * 4;
    off = (off + 255) & ~(size_t)255;
    uint* bins  = (uint*)(ws + off); off += (size_t)NBKT * BCAP * 4;
    int*  col   = (int*)(ws + off);  off += (size_t)NEDGE * 4;
    off = (off + 255) & ~(size_t)255;
    ushort* Xb   = (ushort*)(ws + off); off += (size_t)NNODE * F * 2;
    off = (off + 255) & ~(size_t)255;
    ushort* H1   = (ushort*)(ws + off); off += (size_t)NNODE * F * 2;
    off = (off + 255) & ~(size_t)255;
    ushort* H2   = (ushort*)(ws + off); off += (size_t)NNODE * F * 2;
    off = (off + 255) & ~(size_t)255;
    ushort* Agg  = (ushort*)(ws + off); off += (size_t)NNODE * F * 2;
    off = (off + 255) & ~(size_t)255;
    ushort* G3   = (ushort*)(ws + off); off += (size_t)NNODE * CLS * 2;
    off = (off + 255) & ~(size_t)255;
    ushort* AggG = (ushort*)(ws + off); off += (size_t)NNODE * CLS * 2;
    off = (off + 255) & ~(size_t)255;
    float*  H3   = (float*)(ws + off);  off += (size_t)NNODE * CLS * 4;
    off = (off + 255) & ~(size_t)255;
    ushort* Wb1s = (ushort*)(ws + off); off += 16384 * 2;
    ushort* Wb1n = (ushort*)(ws + off); off += 16384 * 2;
    ushort* Wb2s = (ushort*)(ws + off); off += 16384 * 2;
    ushort* Wb2n = (ushort*)(ws + off); off += 16384 * 2;
    ushort* Wb3s = (ushort*)(ws + off); off += 2048 * 2;
    ushort* Wb3n = (ushort*)(ws + off); off += 2048 * 2;

    hipMemsetAsync(gcount, 0, 512 * 4, stream);

    k_cast<<<NNODE * F / 4 / 256, 256, 0, stream>>>(x, Xb);
    k_wcast<<<272, 256, 0, stream>>>(W1s, W1n, W2s, W2n, W3s, W3n,
                                     Wb1s, Wb1n, Wb2s, Wb2n, Wb3s, Wb3n);

    k_bin<<<NTB, 256, 0, stream>>>(src, dst, bins, gcount);
    k_bscan<<<1, 256, 0, stream>>>(gcount, ebase);
    k_build<<<NBKT, 256, 0, stream>>>(bins, gcount, ebase, rp, col);

    k_agg<<<NNODE / 16, 256, 0, stream>>>(Xb, rp, col, Agg);
    k_gemm128<<<(NNODE + 127) / 128, 256, 0, stream>>>(Xb, Agg, Wb1s, Wb1n, b1, H1);

    k_agg<<<NNODE / 16, 256, 0, stream>>>(H1, rp, col, Agg);
    k_gemm128<<<(NNODE + 127) / 128, 256, 0, stream>>>(H1, Agg, Wb2s, Wb2n, b2, H2);

    k_gemmN16<<<(NNODE + 255) / 256, 256, 0, stream>>>(H2, Wb3n, G3);
    k_agg16<<<(NNODE + 127) / 128, 256, 0, stream>>>(G3, rp, col, AggG);
    k_gemm16s<<<(NNODE + 255) / 256, 256, 0, stream>>>(H2, Wb3s, AggG, b3, H3);

    k_score<<<(EPOS + ENEG + 255) / 256, 256, 0, stream>>>(H3, pos_u, pos_v,
                                                           neg_u, neg_v, out);
}